// Round 14
// baseline (2096.880 us; speedup 1.0000x reference)
//
#include <hip/hip_runtime.h>
#include <hip/hip_bf16.h>
#include <math.h>

// ---------------- constants ----------------
#define NB 32
#define NT 20
#define NV 30
#define JLD 64
#define DM 1280
#define DTR_ 1920
#define DI 2560
#define DSTATE 16
#define DTRANK 80
#define TEMPD 512
#define NHEAD_ 8
#define DH 240

__constant__ int d_VORDER[30] = {9,8,7,10,11,12,11,10,7,13,14,15,14,13,7,6,0,1,2,1,0,6,3,4,5,4,3,6,7,8};
__constant__ int d_REV[16]    = {20,19,18,26,25,24,27,28,29,0,7,6,5,13,12,11};

typedef unsigned short u16;
typedef __bf16 bf16x8 __attribute__((ext_vector_type(8)));
typedef float f32x4  __attribute__((ext_vector_type(4)));
typedef float fv4    __attribute__((ext_vector_type(4)));   // nt-capable float4
typedef unsigned int uv4 __attribute__((ext_vector_type(4))); // nt-capable uint4

__device__ __forceinline__ float siluf(float x){ return x / (1.f + expf(-x)); }
__device__ __forceinline__ float geluf(float x){
    float x3 = x*x*x;
    return 0.5f*x*(1.f + tanhf(0.7978845608028654f*(x + 0.044715f*x3)));
}
__device__ __forceinline__ float softplusf(float x){
    return fmaxf(x, 0.f) + log1pf(expf(-fabsf(x)));
}
__device__ __forceinline__ u16 bfbits(float x){
    return __builtin_bit_cast(u16, (__bf16)x);
}

__device__ __forceinline__ void gload16(const void* g, void* l){
    __builtin_amdgcn_global_load_lds(
        (const __attribute__((address_space(1))) void*)g,
        (__attribute__((address_space(3))) void*)l, 16, 0, 0);
}

__device__ __forceinline__ float blockReduceSum(float v){
    #pragma unroll
    for (int off = 32; off > 0; off >>= 1) v += __shfl_down(v, off, 64);
    __shared__ float sred[4];
    __shared__ float stot;
    int w = threadIdx.x >> 6;
    if ((threadIdx.x & 63) == 0) sred[w] = v;
    __syncthreads();
    if (threadIdx.x == 0) stot = sred[0] + sred[1] + sred[2] + sred[3];
    __syncthreads();
    return stot;
}

enum { ACT_NONE=0, ACT_SILU=1, ACT_GELU=2, ACT_SOFTPLUS=3 };
// MODE: 0 store f32 | 1 += f32 | 2 atomicAdd f32 (+aux if non-null) | 3 store f32+bf16
//       4 store bf16 | 5 C += v + aux | 6 C += v, also write result to aux

// ---------------- bf16 MFMA GEMM, global_load_lds + counted vmcnt ----------------
template<int BM, int ACT, int MODE>
__device__ __forceinline__ void gemm_dev(
    const u16* __restrict__ A, int lda,
    const u16* __restrict__ B, int ldb,
    const float* __restrict__ bias,
    float* __restrict__ C, int ldc,
    u16* __restrict__ Cbf, int ldcb,
    float* __restrict__ aux,
    int M, int N, int KT, int bm, int bn, int ktb)
{
    constexpr int HALF = (BM + 128) * 128;
    constexpr int L    = (BM + 128) * 8 / 256;
    constexpr int MI   = BM / 32;

    __shared__ char lds[2 * HALF];

    const int tid = threadIdx.x, lane = tid & 63, wv = tid >> 6;
    const int wm = (wv >> 1) * (BM / 2), wn = (wv & 1) * 64;

    f32x4 acc[MI][4];
    #pragma unroll
    for (int i = 0; i < MI; ++i)
        #pragma unroll
        for (int j = 0; j < 4; ++j) acc[i][j] = (f32x4){0.f,0.f,0.f,0.f};

    auto stage = [&](int buf, int kt){
        const int kofs = kt * 64;
        #pragma unroll
        for (int i = 0; i < L; ++i) {
            int gb = i*256 + wv*64;
            int g  = gb + lane;
            const u16* src;
            if (i*256 < BM*8) {
                int row = g >> 3, slot = g & 7;
                src = A + (size_t)(bm + row)*lda + kofs + ((slot ^ (row & 7)) << 3);
            } else {
                int g2 = g - BM*8;
                int row = g2 >> 3, slot = g2 & 7;
                src = B + (size_t)(bn + row)*ldb + kofs + ((slot ^ (row & 7)) << 3);
            }
            gload16(src, lds + buf*HALF + gb*16);
        }
    };
    auto compute = [&](int buf){
        const char* Ab = lds + buf*HALF;
        const char* Bb = Ab + BM*128;
        #pragma unroll
        for (int kk = 0; kk < 2; ++kk) {
            int ks = kk*4 + (lane >> 4);
            bf16x8 af[MI], bfr[4];
            #pragma unroll
            for (int mi = 0; mi < MI; ++mi) {
                int row = wm + mi*16 + (lane & 15);
                af[mi] = *(const bf16x8*)(Ab + row*128 + ((ks ^ (row & 7)) << 4));
            }
            #pragma unroll
            for (int ni = 0; ni < 4; ++ni) {
                int n = wn + ni*16 + (lane & 15);
                bfr[ni] = *(const bf16x8*)(Bb + n*128 + ((ks ^ (n & 7)) << 4));
            }
            #pragma unroll
            for (int mi = 0; mi < MI; ++mi)
                #pragma unroll
                for (int ni = 0; ni < 4; ++ni)
                    acc[mi][ni] = __builtin_amdgcn_mfma_f32_16x16x32_bf16(
                        af[mi], bfr[ni], acc[mi][ni], 0, 0, 0);
        }
    };

    stage(0, ktb);
    int cur = 0;
    for (int t = 0; t < KT; ++t) {
        if (t + 1 < KT) {
            stage(cur ^ 1, ktb + t + 1);
            if constexpr (BM == 32) asm volatile("s_waitcnt vmcnt(5)" ::: "memory");
            else                    asm volatile("s_waitcnt vmcnt(6)" ::: "memory");
        } else {
            asm volatile("s_waitcnt vmcnt(0)" ::: "memory");
        }
        __builtin_amdgcn_sched_barrier(0);
        __builtin_amdgcn_s_barrier();
        __builtin_amdgcn_sched_barrier(0);
        compute(cur);
        __builtin_amdgcn_sched_barrier(0);
        __builtin_amdgcn_s_barrier();
        __builtin_amdgcn_sched_barrier(0);
        cur ^= 1;
    }

    const int rb = (lane >> 4) * 4, cb = lane & 15;
    #pragma unroll
    for (int mi = 0; mi < MI; ++mi) {
        #pragma unroll
        for (int r = 0; r < 4; ++r) {
            int row = bm + wm + mi*16 + rb + r;
            #pragma unroll
            for (int ni = 0; ni < 4; ++ni) {
                int col = bn + wn + ni*16 + cb;
                if (col >= N) continue;
                float v = acc[mi][ni][r];
                if (bias) v += bias[col];
                if (ACT == ACT_SILU)     v = siluf(v);
                if (ACT == ACT_GELU)     v = geluf(v);
                if (ACT == ACT_SOFTPLUS) v = softplusf(v);
                size_t idx = (size_t)row*ldc + col;
                if (MODE == 1)      C[idx] += v;
                else if (MODE == 2) { float t2 = v; if (aux) t2 += aux[idx]; atomicAdd(&C[idx], t2); }
                else if (MODE == 5) C[idx] = C[idx] + v + aux[idx];
                else if (MODE == 6) { float t2 = C[idx] + v; C[idx] = t2; aux[idx] = t2; }
                else {
                    if (MODE != 4) C[idx] = v;
                    if (MODE >= 3) Cbf[(size_t)row*ldcb + col] = bfbits(v);
                }
            }
        }
    }
    (void)M;
}

template<int BM, int ACT, int MODE>
__global__ __launch_bounds__(256) void gemm_g_bk(
    const u16* __restrict__ A, int lda, const u16* __restrict__ B, int ldb,
    const float* __restrict__ bias, float* __restrict__ C, int ldc,
    u16* __restrict__ Cbf, int ldcb, float* __restrict__ aux,
    int M, int N, int KT)
{
    if ((int)blockIdx.x * 128 >= N) return;   // XCD-pad idle tile
    const float* bias_eff = (blockIdx.z == 0) ? bias : nullptr;
    float*       aux_eff  = (blockIdx.z == 0) ? aux  : nullptr;
    gemm_dev<BM,ACT,MODE>(A,lda,B,ldb,bias_eff,C,ldc,Cbf,ldcb,aux_eff,M,N,KT,
                          blockIdx.y*BM, blockIdx.x*128, blockIdx.z*KT);
}

__global__ __launch_bounds__(256) void gemm_qkv_bk(
    const u16* __restrict__ A, const u16* __restrict__ Wqkv,
    const float* __restrict__ bq, const float* __restrict__ bk2, const float* __restrict__ bv,
    float* __restrict__ oq, float* __restrict__ ok2, float* __restrict__ ov)
{
    if ((int)blockIdx.x * 128 >= DTR_) return;   // XCD-pad idle tile (gx=16)
    int z = blockIdx.z;
    const float* bb = (z == 0) ? bq : (z == 1) ? bk2 : bv;
    float*       cc = (z == 0) ? oq : (z == 1) ? ok2 : ov;
    gemm_dev<64,ACT_NONE,0>(A, DTR_, Wqkv + (size_t)z*DTR_*DTR_, DTR_, bb,
                            cc, DTR_, nullptr, 0, nullptr, NB*NT, DTR_, 30,
                            blockIdx.y*64, blockIdx.x*128, 0);
}

__global__ __launch_bounds__(256) void gemm_memb_bk(
    const u16* __restrict__ A, const u16* __restrict__ W,
    const float* __restrict__ bias, float* __restrict__ Cc)
{
    int z = blockIdx.z;
    gemm_dev<32,ACT_NONE,0>(A, TEMPD, W + (size_t)z*DM*TEMPD, TEMPD, bias + (size_t)z*DM,
                            Cc + (size_t)z*NB*DM, DM, nullptr, 0, nullptr, NB, DM, 8,
                            blockIdx.y*32, blockIdx.x*128, 0);
}

__global__ __launch_bounds__(256) void gemm_ssb_bk(
    const u16* __restrict__ A, const u16* __restrict__ W,
    const float* __restrict__ b1, const float* __restrict__ b2, float* __restrict__ Cc)
{
    int z = blockIdx.z;
    const float* bb = (z < 4) ? b1 + (size_t)z*2*DTR_ : b2 + (size_t)(z-4)*2*DTR_;
    gemm_dev<32,ACT_NONE,0>(A, TEMPD, W + (size_t)z*2*DTR_*TEMPD, TEMPD, bb,
                            Cc + (size_t)z*NB*2*DTR_, 2*DTR_, nullptr, 0, nullptr, NB, 2*DTR_, 8,
                            blockIdx.y*32, blockIdx.x*128, 0);
}

// ---------------- weight convert (R7 structure + non-temporal access) ----------------
struct ConvEnt { const float* src; u16* dst; int K, N, Kp, Np, tile0; };
struct ConvTab { ConvEnt e[64]; int n; };

__global__ __launch_bounds__(256) void wconv_k(ConvTab tab){
    int t = blockIdx.x;
    int i = 0;
    while (i + 1 < tab.n && tab.e[i+1].tile0 <= t) ++i;
    const float* src = tab.e[i].src;
    u16* dst = tab.e[i].dst;
    const int K = tab.e[i].K, N = tab.e[i].N, Kp = tab.e[i].Kp, Np = tab.e[i].Np;
    int lt = t - tab.e[i].tile0;
    int nx = Np >> 6;
    int n0 = (lt % nx) << 6, k0 = (lt / nx) << 6;

    __shared__ u16 tile[64][72];
    const int tid = threadIdx.x;
    {
        int r = tid >> 2, cs = (tid & 3) << 4;
        int gk = k0 + r;
        #pragma unroll
        for (int j = 0; j < 16; j += 4) {
            int gn = n0 + cs + j;
            fv4 v = (fv4){0.f,0.f,0.f,0.f};
            if (gk < K) {
                if (gn + 3 < N)
                    v = __builtin_nontemporal_load((const fv4*)(src + (size_t)gk*N + gn));
                else {
                    float tmp[4] = {0.f,0.f,0.f,0.f};
                    for (int e2 = 0; e2 < 4; ++e2) if (gn + e2 < N) tmp[e2] = src[(size_t)gk*N + gn + e2];
                    v = (fv4){tmp[0],tmp[1],tmp[2],tmp[3]};
                }
            }
            tile[r][cs+j+0] = bfbits(v.x);
            tile[r][cs+j+1] = bfbits(v.y);
            tile[r][cs+j+2] = bfbits(v.z);
            tile[r][cs+j+3] = bfbits(v.w);
        }
    }
    __syncthreads();
    {
        int n = tid >> 2, ks = (tid & 3) << 4;
        u16 outv[16];
        #pragma unroll
        for (int j = 0; j < 16; ++j) outv[j] = tile[ks + j][n];
        u16* dp = dst + (size_t)(n0 + n)*Kp + k0 + ks;
        __builtin_nontemporal_store(*(uv4*)&outv[0], (uv4*)dp);
        __builtin_nontemporal_store(*(uv4*)&outv[8], (uv4*)(dp + 8));
    }
}

// ---------------- small kernels ----------------

__global__ void tsemb_k(const int* __restrict__ t, u16* __restrict__ o){
    int b = blockIdx.x, j = threadIdx.x;   // 640
    float f = expf(-9.210340371976184f * (float)j / 640.f);
    float a = (float)t[b] * f;
    o[b*DM + j]       = bfbits(cosf(a));
    o[b*DM + 640 + j] = bfbits(sinf(a));
}

__global__ void silu_bf_v(const float* __restrict__ a, u16* __restrict__ o, int n){
    int i = blockIdx.x*256 + threadIdx.x; if (i < n) o[i] = bfbits(siluf(a[i]));
}
__global__ void zero_k(float* __restrict__ p, int n){
    int i = blockIdx.x*256 + threadIdx.x; if (i < n) p[i] = 0.f;
}

__global__ void embed_k(const float* __restrict__ x, const float* __restrict__ seq_emb,
                        const float* __restrict__ eW, const float* __restrict__ eb,
                        float* __restrict__ h, float* __restrict__ pre0){
    int i = blockIdx.x;            // b*600 + t*30 + vo
    int c = threadIdx.x;           // 64
    int vo = i % 30; int bt = i / 30; int t = bt % 20; int b = bt / 20;
    int v = d_VORDER[vo];
    const float* xp = x + (size_t)(b*20 + t)*48 + v*3;
    float val = eb[c] + seq_emb[(size_t)(t*16 + v)*64 + c]
              + xp[0]*eW[c] + xp[1]*eW[64 + c] + xp[2]*eW[128 + c];
    h[(size_t)i*64 + c] = val;
    pre0[(size_t)i*64 + c] = val;
}

__global__ void rms_t_k(const float* __restrict__ h, const float* __restrict__ w,
                        const float* __restrict__ memb,
                        float* __restrict__ hm, u16* __restrict__ hn_bf){
    int row = blockIdx.x;          // b*30+v
    int b = row / 30, v = row % 30;
    float ss = 0.f;
    for (int idx = threadIdx.x; idx < DM; idx += 256) {
        int t = idx >> 6, c = idx & 63;
        float val = h[((size_t)(b*20 + t)*30 + v)*64 + c];
        hm[(size_t)row*DM + idx] = val;
        ss += val*val;
    }
    ss = blockReduceSum(ss);
    float rs = rsqrtf(ss/(float)DM + 1e-5f);
    const float* ap = memb + (size_t)b*DM;
    for (int idx = threadIdx.x; idx < DM; idx += 256) {
        float val = hm[(size_t)row*DM + idx];
        hn_bf[(size_t)row*DM + idx] = bfbits(val*rs*w[idx] + ap[idx]);
    }
}

__global__ void hm2ht_ln_k(const float* __restrict__ hm, const float* __restrict__ w,
                           const float* __restrict__ bias,
                           float* __restrict__ h, u16* __restrict__ xn_bf){
    int row = blockIdx.x;          // b*20+t
    int b = row / 20, t = row % 20;
    float s1 = 0.f, s2 = 0.f;
    for (int idx = threadIdx.x; idx < DTR_; idx += 256) {
        int v = idx >> 6, c = idx & 63;
        float val = hm[((size_t)(b*30 + v))*DM + t*64 + c];
        h[(size_t)row*DTR_ + idx] = val;
        s1 += val; s2 += val*val;
    }
    s1 = blockReduceSum(s1);
    s2 = blockReduceSum(s2);
    float m = s1/(float)DTR_, var = s2/(float)DTR_ - m*m, rs = rsqrtf(var + 1e-5f);
    for (int idx = threadIdx.x; idx < DTR_; idx += 256) {
        float val = h[(size_t)row*DTR_ + idx];
        xn_bf[(size_t)row*DTR_ + idx] = bfbits((val - m)*rs*w[idx] + bias[idx]);
    }
}

__global__ void ln_bf_k(const float* __restrict__ x, const float* __restrict__ w,
                        const float* __restrict__ b, u16* __restrict__ obf, int D){
    int row = blockIdx.x;
    const float* xr = x + (size_t)row*D;
    float s1 = 0.f, s2 = 0.f;
    for (int i = threadIdx.x; i < D; i += 256){ float v = xr[i]; s1 += v; s2 += v*v; }
    s1 = blockReduceSum(s1);
    s2 = blockReduceSum(s2);
    float m = s1/(float)D, var = s2/(float)D - m*m, rs = rsqrtf(var + 1e-5f);
    for (int i = threadIdx.x; i < D; i += 256)
        obf[(size_t)row*D + i] = bfbits((xr[i] - m)*rs*w[i] + b[i]);
}

__global__ void convsilu_k(const float* __restrict__ xz, const float* __restrict__ cw,
                           const float* __restrict__ cb,
                           float* __restrict__ xc, u16* __restrict__ xcbf){
    int idx = blockIdx.x*256 + threadIdx.x;
    if (idx >= NB*NV*DI) return;
    int d = idx % DI; int bl = idx / DI; int l = bl % NV; int b = bl / NV;
    float acc = cb[d];
    #pragma unroll
    for (int k = 0; k < 4; ++k) {
        int ls = l - 3 + k;
        if (ls >= 0) acc += xz[((size_t)(b*NV + ls))*(2*DI) + d] * cw[d*4 + k];
    }
    float v = siluf(acc);
    xc[idx] = v;
    xcbf[idx] = bfbits(v);
}

__global__ void dbcconv_k(const float* __restrict__ dbc, u16* __restrict__ dbf){
    int i = blockIdx.x*256 + threadIdx.x;
    if (i >= NB*NV*128) return;
    int r = i >> 7, c = i & 127;
    dbf[i] = bfbits(c < 112 ? dbc[(size_t)r*112 + c] : 0.f);
}

__global__ __launch_bounds__(256) void scan_k(
    const float* __restrict__ delta, const float* __restrict__ dbc,
    const float* __restrict__ xc, const float* __restrict__ xz,
    const float* __restrict__ A_log, const float* __restrict__ Dp,
    u16* __restrict__ y2bf)
{
    __shared__ float sBC[30][32];
    int b = blockIdx.x / 10;
    int dblk = blockIdx.x % 10;
    int tid = threadIdx.x;
    for (int i = tid; i < 30*32; i += 256) {
        int l = i >> 5, j = i & 31;
        sBC[l][j] = dbc[((size_t)(b*NV + l))*112 + 80 + j];
    }
    __syncthreads();
    int d = dblk*256 + tid;
    float aA[16], s[16];
    #pragma unroll
    for (int n = 0; n < 16; ++n){ aA[n] = -expf(A_log[(size_t)d*16 + n]); s[n] = 0.f; }
    float dpv = Dp[d];
    for (int l = 0; l < NV; ++l) {
        size_t base = (size_t)(b*NV + l);
        float dv   = delta[base*DI + d];
        float xcv  = xc[base*DI + d];
        float resv = xz[base*(2*DI) + DI + d];
        float y = 0.f;
        #pragma unroll
        for (int n = 0; n < 16; ++n) {
            float dA = expf(dv*aA[n]);
            s[n] = dA*s[n] + dv*sBC[l][n]*xcv;
            y = fmaf(s[n], sBC[l][16 + n], y);
        }
        y2bf[base*DI + d] = bfbits((y + xcv*dpv) * siluf(resv));
    }
}

__global__ __launch_bounds__(64) void attn_k(const float* __restrict__ q,
                                             const float* __restrict__ k,
                                             const float* __restrict__ v,
                                             float* __restrict__ o){
    int idx = blockIdx.x;          // b*160 + t*8 + h
    int h = idx % 8; int bt = idx / 8; int t = bt % 20; int b = bt / 20;
    int lane = threadIdx.x;
    const float* qp = q + ((size_t)(b*20 + t))*DTR_ + h*DH;
    float qr[4];
    #pragma unroll
    for (int i = 0; i < 4; ++i){ int j = lane + i*64; qr[i] = (j < DH) ? qp[j] : 0.f; }
    __shared__ float sc[20];
    const float scale = 0.06454972243679028f;
    for (int s2 = 0; s2 < 20; ++s2) {
        const float* kp = k + ((size_t)(b*20 + s2))*DTR_ + h*DH;
        float p = 0.f;
        #pragma unroll
        for (int i = 0; i < 4; ++i){ int j = lane + i*64; if (j < DH) p = fmaf(qr[i], kp[j], p); }
        #pragma unroll
        for (int off = 32; off > 0; off >>= 1) p += __shfl_down(p, off, 64);
        if (lane == 0) sc[s2] = p*scale;
    }
    __syncthreads();
    float m = -1e30f;
    #pragma unroll
    for (int s2 = 0; s2 < 20; ++s2) m = fmaxf(m, sc[s2]);
    float ps[20]; float sum = 0.f;
    #pragma unroll
    for (int s2 = 0; s2 < 20; ++s2){ ps[s2] = expf(sc[s2] - m); sum += ps[s2]; }
    float inv = 1.f/sum;
    float acc[4] = {0.f,0.f,0.f,0.f};
    for (int s2 = 0; s2 < 20; ++s2) {
        const float* vp = v + ((size_t)(b*20 + s2))*DTR_ + h*DH;
        float w2 = ps[s2]*inv;
        #pragma unroll
        for (int i = 0; i < 4; ++i){ int j = lane + i*64; if (j < DH) acc[i] = fmaf(w2, vp[j], acc[i]); }
    }
    float* op = o + ((size_t)(b*20 + t))*DTR_ + h*DH;
    #pragma unroll
    for (int i = 0; i < 4; ++i){ int j = lane + i*64; if (j < DH) op[j] = acc[i]; }
}

__global__ void sty_ln_k(const float* __restrict__ x, const float* __restrict__ lw,
                         const float* __restrict__ lb, const float* __restrict__ ss,
                         u16* __restrict__ obf){
    int row = blockIdx.x;          // b*20+t
    int b = row / 20;
    const float* xr = x + (size_t)row*DTR_;
    float s1 = 0.f, s2 = 0.f;
    for (int i = threadIdx.x; i < DTR_; i += 256){ float v = xr[i]; s1 += v; s2 += v*v; }
    s1 = blockReduceSum(s1);
    s2 = blockReduceSum(s2);
    float m = s1/(float)DTR_, var = s2/(float)DTR_ - m*m, rs = rsqrtf(var + 1e-5f);
    const float* sb = ss + (size_t)b*(2*DTR_);
    for (int i = threadIdx.x; i < DTR_; i += 256) {
        float v = (xr[i] - m)*rs*lw[i] + lb[i];
        v = v*(1.f + sb[i]) + sb[DTR_ + i];
        obf[(size_t)row*DTR_ + i] = bfbits(siluf(v));
    }
}

__global__ void rms_f_k(const float* __restrict__ x, const float* __restrict__ w,
                        float* __restrict__ o, int D){
    int row = blockIdx.x;
    const float* xr = x + (size_t)row*D;
    float ss = 0.f;
    for (int i = threadIdx.x; i < D; i += 256){ float v = xr[i]; ss += v*v; }
    ss = blockReduceSum(ss);
    float rs = rsqrtf(ss/(float)D + 1e-5f);
    for (int i = threadIdx.x; i < D; i += 256)
        o[(size_t)row*D + i] = xr[i]*rs*w[i];
}

__global__ void head_k(const float* __restrict__ fr, const float* __restrict__ W,
                       const float* __restrict__ bias, float* __restrict__ out){
    int row = blockIdx.x;          // b*20+t
    int tid = threadIdx.x;         // 48
    int v = tid/3, j = tid%3;
    const float* g = fr + (size_t)row*DTR_ + d_REV[v]*64;
    float acc = bias[j];
    #pragma unroll
    for (int c = 0; c < 64; ++c) acc = fmaf(g[c], W[c*3 + j], acc);
    out[(size_t)row*48 + tid] = acc;
}

// ---------------- host-side GEMM launcher ----------------
template<int BM, int ACT, int MODE>
static void G(hipStream_t st, const u16* A, int lda, const u16* B, int ldb,
              const float* bias, float* C, int ldc, u16* Cbf, int ldcb,
              int M, int N, int KT, int splitZ = 1, float* aux = nullptr)
{
    int gx = (N + 127)/128;
    if (gx > 8) gx = (gx + 7) & ~7;   // XCD-concentrate B panels (stride % 8 == 0)
    dim3 g(gx, M/BM, splitZ), b(256);
    gemm_g_bk<BM,ACT,MODE><<<g, b, 0, st>>>(A,lda,B,ldb,bias,C,ldc,Cbf,ldcb,aux,M,N,KT);
}

// ---------------- orchestration ----------------
extern "C" void kernel_launch(void* const* d_in, const int* in_sizes, int n_in,
                              void* d_out, int out_size, void* d_ws, size_t ws_size,
                              hipStream_t stream)
{
    const float* x        = (const float*)d_in[0];
    const int*   tst      = (const int*)  d_in[1];
    const float* seq_emb  = (const float*)d_in[2];
    const float* emb_W    = (const float*)d_in[3];
    const float* emb_b    = (const float*)d_in[4];
    const float* time_W1  = (const float*)d_in[5];
    const float* time_b1  = (const float*)d_in[6];
    const float* time_W2  = (const float*)d_in[7];
    const float* time_b2  = (const float*)d_in[8];
    const float* m_norm_w = (const float*)d_in[9];
    const float* m_emb_W  = (const float*)d_in[10];
    const float* m_emb_b  = (const float*)d_in[11];
    const float* m_in_W   = (const float*)d_in[12];
    const float* m_conv_w = (const float*)d_in[13];
    const float* m_conv_b = (const float*)d_in[14];
    const float* m_xproj_W= (const float*)d_in[15];
    const float* m_dt_W   = (const float*)d_in[16];
    const float* m_dt_b   = (const float*)d_in[17];
    const float* m_A_log  = (const float*)d_in[18];
    const float* m_D      = (const float*)d_in[19];
    const float* m_out_W  = (const float*)d_in[20];
    const float* t_ln1_w  = (const float*)d_in[21];
    const float* t_ln1_b  = (const float*)d_in[22];
    const float* t_Wq     = (const float*)d_in[23];
    const float* t_bq     = (const float*)d_in[24];
    const float* t_Wk     = (const float*)d_in[25];
    const float* t_bk     = (const float*)d_in[26];
    const float* t_Wv     = (const float*)d_in[27];
    const float* t_bv     = (const float*)d_in[28];
    const float* t_s1_eW  = (const float*)d_in[29];
    const float* t_s1_eb  = (const float*)d_in[30];
    const float* t_s1_lw  = (const float*)d_in[31];
    const float* t_s1_lb  = (const float*)d_in[32];
    const float* t_s1_oW  = (const float*)d_in[33];
    const float* t_s1_ob  = (const float*)d_in[34];
    const float* t_ln2_w  = (const float*)d_in[35];
    const float* t_ln2_b  = (const float*)d_in[36];
    const float* t_fW1    = (const float*)d_in[37];
    const float* t_fb1    = (const float*)d_in[38];
    const float* t_fW2    = (const float*)d_in[39];
    const float* t_fb2    = (const float*)d_in[40];
    const float* t_s2_eW  = (const float*)d_in[41];
    const float* t_s2_eb  = (const float*)d_in[42];
    const float* t_s2_lw  = (const float*)d_in[43];
    const float* t_s2_lb  = (const float*)d_in[44];
    const float* t_s2_oW  = (const float*)d_in[45];
    const float* t_s2_ob  = (const float*)d_in[46];
    const float* normf_w  = (const float*)d_in[47];
    const float* head_W   = (const float*)d_in[48];
    const float* head_b   = (const float*)d_in[49];

    float* ws = (float*)d_ws;
    size_t off = 0;
    auto allocf = [&](size_t n){ float* p = ws + off; off += (n + 3) & ~(size_t)3; return p; };
    auto allocu = [&](size_t n){ return (u16*)allocf((n + 1) / 2); };

    const size_t HSZ = (size_t)NB*NT*NV*JLD;      // 1,228,800
    // fp32
    float* emb   = allocf((size_t)NB*TEMPD);
    float* memb4 = allocf((size_t)4*NB*DM);
    float* ssb8  = allocf((size_t)8*NB*2*DTR_);
    float* h     = allocf(HSZ);
    float* pre0  = allocf(HSZ);
    float* pre1  = allocf(HSZ);
    float* hm    = allocf(HSZ);
    float* qb    = allocf(HSZ);
    float* kb    = allocf(HSZ);
    float* vb    = allocf(HSZ);
    float* aty   = allocf(HSZ);
    float* fr    = allocf(HSZ);
    float* xz    = allocf((size_t)NB*NV*2*DI);
    float* xcb   = allocf((size_t)NB*NV*DI);
    float* dbc   = allocf((size_t)NB*NV*112);
    float* delta = allocf((size_t)NB*NV*DI);
    // bf16 activations
    u16* embt_bf = allocu((size_t)NB*DM);
    u16* emb1_bf = allocu((size_t)NB*TEMPD);
    u16* emb_bf  = allocu((size_t)NB*TEMPD);
    u16* semb_bf = allocu((size_t)NB*TEMPD);
    u16* hn_bf   = allocu((size_t)NB*NV*DM);
    u16* xcb_bf  = allocu((size_t)NB*NV*DI);
    u16* dbc_bf  = allocu((size_t)NB*NV*128);
    u16* y2_bf   = allocu((size_t)NB*NV*DI);
    u16* xn_bf   = allocu((size_t)NB*NT*DTR_);
    u16* sty_bf  = allocu((size_t)NB*NT*DTR_);
    u16* mid_bf  = allocu((size_t)NB*NT*DI);
    // bf16 weights (upfront, shared)
    u16* tw1   = allocu((size_t)TEMPD*DM);
    u16* tw2   = allocu((size_t)TEMPD*TEMPD);
    u16* membW = allocu((size_t)4*DM*TEMPD);
    u16* ssbW  = allocu((size_t)8*2*DTR_*TEMPD);
    // bf16 weight slabs, all 4 layers
    const size_t SLAB = (size_t)2*DI*DM + 128*DI + DI*128 + DM*DI
                      + (size_t)3*DTR_*DTR_ + 2*(size_t)DTR_*DTR_
                      + (size_t)DI*DTR_ + (size_t)DTR_*DI;
    u16* slab0 = allocu(SLAB*4);
    (void)ws_size; (void)in_sizes; (void)n_in; (void)out_size;

    // per-layer slab pointers
    u16 *s_in[4], *s_xp[4], *s_dt[4], *s_out[4], *s_qkv[4], *s_s1o[4], *s_s2o[4], *s_f1[4], *s_f2[4];
    for (int l = 0; l < 4; ++l) {
        u16* p = slab0 + SLAB*l;
        s_in[l]  = p; p += (size_t)2*DI*DM;
        s_xp[l]  = p; p += (size_t)128*DI;
        s_dt[l]  = p; p += (size_t)DI*128;
        s_out[l] = p; p += (size_t)DM*DI;
        s_qkv[l] = p; p += (size_t)3*DTR_*DTR_;
        s_s1o[l] = p; p += (size_t)DTR_*DTR_;
        s_s2o[l] = p; p += (size_t)DTR_*DTR_;
        s_f1[l]  = p; p += (size_t)DI*DTR_;
        s_f2[l]  = p;
    }

    auto tiles = [](int Kp, int Np){ return (Np/64)*(Kp/64); };

    // ---- ALL weight conversion in one launch (R7 wconv + nt access) ----
    {
        ConvTab tb; int n = 0, tot = 0;
        auto add = [&](const float* src, u16* dst, int K, int N){
            int Kp = (K + 63) & ~63;
            int Np = (N + 127) & ~127;
            tb.e[n] = {src, dst, K, N, Kp, Np, tot};
            tot += tiles(Kp, Np); ++n;
        };
        add(time_W1, tw1, DM, TEMPD);
        add(time_W2, tw2, TEMPD, TEMPD);
        for (int l = 0; l < 4; ++l)
            add(m_emb_W + (size_t)l*TEMPD*DM, membW + (size_t)l*DM*TEMPD, TEMPD, DM);
        for (int l = 0; l < 4; ++l)
            add(t_s1_eW + (size_t)l*TEMPD*2*DTR_, ssbW + (size_t)l*2*DTR_*TEMPD, TEMPD, 2*DTR_);
        for (int l = 0; l < 4; ++l)
            add(t_s2_eW + (size_t)l*TEMPD*2*DTR_, ssbW + (size_t)(4+l)*2*DTR_*TEMPD, TEMPD, 2*DTR_);
        for (int l = 0; l < 4; ++l) {
            add(m_in_W   + (size_t)l*DM*2*DI,     s_in[l],  DM, 2*DI);
            add(m_xproj_W+ (size_t)l*DI*112,      s_xp[l],  DI, 112);
            add(m_dt_W   + (size_t)l*DTRANK*DI,   s_dt[l],  DTRANK, DI);
            add(m_out_W  + (size_t)l*DI*DM,       s_out[l], DI, DM);
            add(t_Wq     + (size_t)l*DTR_*DTR_,   s_qkv[l],                       DTR_, DTR_);
            add(t_Wk     + (size_t)l*DTR_*DTR_,   s_qkv[l] + (size_t)DTR_*DTR_,   DTR_, DTR_);
            add(t_Wv     + (size_t)l*DTR_*DTR_,   s_qkv[l] + (size_t)2*DTR_*DTR_, DTR_, DTR_);
            add(t_s1_oW  + (size_t)l*DTR_*DTR_,   s_s1o[l], DTR_, DTR_);
            add(t_s2_oW  + (size_t)l*DTR_*DTR_,   s_s2o[l], DTR_, DTR_);
            add(t_fW1    + (size_t)l*DTR_*DI,     s_f1[l],  DTR_, DI);
            add(t_fW2    + (size_t)l*DI*DTR_,     s_f2[l],  DI, DTR_);
        }
        tb.n = n;
        wconv_k<<<tot, 256, 0, stream>>>(tb);
    }

    // ---- time embedding + MLP ----
    tsemb_k<<<NB, 640, 0, stream>>>(tst, embt_bf);
    G<32,ACT_SILU,4>(stream, embt_bf, DM, tw1, DM, time_b1, nullptr, 0, emb1_bf, TEMPD, NB, TEMPD, 20);
    G<32,ACT_NONE,3>(stream, emb1_bf, TEMPD, tw2, TEMPD, time_b2, emb, TEMPD, emb_bf, TEMPD, NB, TEMPD, 8);
    silu_bf_v<<<(NB*TEMPD + 255)/256, 256, 0, stream>>>(emb, semb_bf, NB*TEMPD);

    // ---- hoisted per-layer emb projections ----
    {
        dim3 g1(DM/128, 1, 4), b(256);
        gemm_memb_bk<<<g1, b, 0, stream>>>(emb_bf, membW, m_emb_b, memb4);
        dim3 g2((2*DTR_)/128, 1, 8);
        gemm_ssb_bk<<<g2, b, 0, stream>>>(semb_bf, ssbW, t_s1_eb, t_s2_eb, ssb8);
    }

    // ---- vertex embedding + VORDER gather (writes h and pre0) ----
    embed_k<<<NB*NT*NV, 64, 0, stream>>>(x, seq_emb, emb_W, emb_b, h, pre0);

    for (int i = 0; i < 4; ++i) {
        // ---- mamba half ----
        rms_t_k<<<NB*NV, 256, 0, stream>>>(h, m_norm_w + (size_t)i*DM,
                                           memb4 + (size_t)i*NB*DM, hm, hn_bf);
        // in_W: BM=64 (AI 43), 600 real blocks, nx=40
        G<64,ACT_NONE,0>(stream, hn_bf, DM, s_in[i], DM, nullptr, xz, 2*DI, nullptr, 0, NB*NV, 2*DI, 20);
        convsilu_k<<<(NB*NV*DI + 255)/256, 256, 0, stream>>>(
            xz, m_conv_w + (size_t)i*DI*4, m_conv_b + (size_t)i*DI, xcb, xcb_bf);
        zero_k<<<(NB*NV*112 + 255)/256, 256, 0, stream>>>(dbc, NB*NV*112);
        G<32,ACT_NONE,2>(stream, xcb_bf, DI, s_xp[i], DI, nullptr, dbc, 112, nullptr, 0, NB*NV, 112, 5, 8);
        dbcconv_k<<<(NB*NV*128 + 255)/256, 256, 0, stream>>>(dbc, dbc_bf);
        // dt: BM=32, nx padded 20->24
        G<32,ACT_SOFTPLUS,0>(stream, dbc_bf, 128, s_dt[i], 128, m_dt_b + (size_t)i*DI,
                             delta, DI, nullptr, 0, NB*NV, DI, 2);
        scan_k<<<NB*10, 256, 0, stream>>>(delta, dbc, xcb, xz,
             m_A_log + (size_t)i*DI*DSTATE, m_D + (size_t)i*DI, y2_bf);
        // out: split-K x2, atomic += into hm; nx padded 10->16
        G<32,ACT_NONE,2>(stream, y2_bf, DI, s_out[i], DI, nullptr, hm, DM, nullptr, 0, NB*NV, DM, 20, 2);
        hm2ht_ln_k<<<NB*NT, 256, 0, stream>>>(hm, t_ln1_w + (size_t)i*DTR_, t_ln1_b + (size_t)i*DTR_,
                                              h, xn_bf);

        // ---- transformer half ----
        {
            dim3 g(16, (NB*NT)/64, 3), b(256);   // BM=64: 16x10x3, gx padded 15->16
            gemm_qkv_bk<<<g, b, 0, stream>>>(xn_bf, s_qkv[i],
                t_bq + (size_t)i*DTR_, t_bk + (size_t)i*DTR_, t_bv + (size_t)i*DTR_,
                qb, kb, vb);
        }
        attn_k<<<NB*NT*NHEAD_, 64, 0, stream>>>(qb, kb, vb, aty);

        sty_ln_k<<<NB*NT, 256, 0, stream>>>(aty, t_s1_lw + (size_t)i*DTR_, t_s1_lb + (size_t)i*DTR_,
                                            ssb8 + (size_t)i*NB*2*DTR_, sty_bf);
        // s1o: split-K x2, atomic += into h, bias once; nx padded 15->16
        G<32,ACT_NONE,2>(stream, sty_bf, DTR_, s_s1o[i], DTR_, t_s1_ob + (size_t)i*DTR_,
                         h, DTR_, nullptr, 0, NB*NT, DTR_, 15, 2);

        ln_bf_k<<<NB*NT, 256, 0, stream>>>(h, t_ln2_w + (size_t)i*DTR_, t_ln2_b + (size_t)i*DTR_, xn_bf, DTR_);
        G<32,ACT_GELU,4>(stream, xn_bf, DTR_, s_f1[i], DTR_, t_fb1 + (size_t)i*DI,
                         nullptr, 0, mid_bf, DI, NB*NT, DI, 30);
        // f2: zero aty, then split-K x2 atomic store; nx padded 15->16
        zero_k<<<(int)((HSZ + 255)/256), 256, 0, stream>>>(aty, (int)HSZ);
        G<32,ACT_NONE,2>(stream, mid_bf, DI, s_f2[i], DI, t_fb2 + (size_t)i*DTR_,
                         aty, DTR_, nullptr, 0, NB*NT, DTR_, 20, 2);

        sty_ln_k<<<NB*NT, 256, 0, stream>>>(aty, t_s2_lw + (size_t)i*DTR_, t_s2_lb + (size_t)i*DTR_,
                                            ssb8 + (size_t)(4 + i)*NB*2*DTR_, sty_bf);
        if (i == 0)      // needs the completed sum copied to pre1 -> keep unsplit
            G<32,ACT_NONE,6>(stream, sty_bf, DTR_, s_s2o[i], DTR_, t_s2_ob + (size_t)i*DTR_,
                             h, DTR_, nullptr, 0, NB*NT, DTR_, 30, 1, pre1);
        else if (i == 2) // h += v + pre1 : split-K x2, aux added once by z==0
            G<32,ACT_NONE,2>(stream, sty_bf, DTR_, s_s2o[i], DTR_, t_s2_ob + (size_t)i*DTR_,
                             h, DTR_, nullptr, 0, NB*NT, DTR_, 15, 2, pre1);
        else if (i == 3)
            G<32,ACT_NONE,2>(stream, sty_bf, DTR_, s_s2o[i], DTR_, t_s2_ob + (size_t)i*DTR_,
                             h, DTR_, nullptr, 0, NB*NT, DTR_, 15, 2, pre0);
        else
            G<32,ACT_NONE,2>(stream, sty_bf, DTR_, s_s2o[i], DTR_, t_s2_ob + (size_t)i*DTR_,
                             h, DTR_, nullptr, 0, NB*NT, DTR_, 15, 2);
    }

    // final rmsnorm + REV gather + head
    rms_f_k<<<NB*NT, 256, 0, stream>>>(h, normf_w, fr, DTR_);
    head_k<<<NB*NT, 48, 0, stream>>>(fr, head_W, head_b, (float*)d_out);
}

// Round 15
// 1754.128 us; speedup vs baseline: 1.1954x; 1.1954x over previous
//
#include <hip/hip_runtime.h>
#include <hip/hip_bf16.h>
#include <math.h>

// ---------------- constants ----------------
#define NB 32
#define NT 20
#define NV 30
#define JLD 64
#define DM 1280
#define DTR_ 1920
#define DI 2560
#define DSTATE 16
#define DTRANK 80
#define TEMPD 512
#define NHEAD_ 8
#define DH 240

__constant__ int d_VORDER[30] = {9,8,7,10,11,12,11,10,7,13,14,15,14,13,7,6,0,1,2,1,0,6,3,4,5,4,3,6,7,8};
__constant__ int d_REV[16]    = {20,19,18,26,25,24,27,28,29,0,7,6,5,13,12,11};

typedef unsigned short u16;
typedef __bf16 bf16x8 __attribute__((ext_vector_type(8)));
typedef float f32x4  __attribute__((ext_vector_type(4)));

__device__ __forceinline__ float siluf(float x){ return x / (1.f + expf(-x)); }
__device__ __forceinline__ float geluf(float x){
    float x3 = x*x*x;
    return 0.5f*x*(1.f + tanhf(0.7978845608028654f*(x + 0.044715f*x3)));
}
__device__ __forceinline__ float softplusf(float x){
    return fmaxf(x, 0.f) + log1pf(expf(-fabsf(x)));
}
__device__ __forceinline__ u16 bfbits(float x){
    return __builtin_bit_cast(u16, (__bf16)x);
}

__device__ __forceinline__ void gload16(const void* g, void* l){
    __builtin_amdgcn_global_load_lds(
        (const __attribute__((address_space(1))) void*)g,
        (__attribute__((address_space(3))) void*)l, 16, 0, 0);
}

__device__ __forceinline__ float blockReduceSum(float v){
    #pragma unroll
    for (int off = 32; off > 0; off >>= 1) v += __shfl_down(v, off, 64);
    __shared__ float sred[4];
    __shared__ float stot;
    int w = threadIdx.x >> 6;
    if ((threadIdx.x & 63) == 0) sred[w] = v;
    __syncthreads();
    if (threadIdx.x == 0) stot = sred[0] + sred[1] + sred[2] + sred[3];
    __syncthreads();
    return stot;
}

enum { ACT_NONE=0, ACT_SILU=1, ACT_GELU=2, ACT_SOFTPLUS=3 };
// MODE: 0 store f32 | 1 += f32 | 2 atomicAdd f32 (+aux if non-null) | 3 store f32+bf16
//       4 store bf16 | 5 C += v + aux | 6 C += v, also write result to aux

// ---------------- bf16 MFMA GEMM, global_load_lds + counted vmcnt ----------------
template<int BM, int ACT, int MODE>
__device__ __forceinline__ void gemm_dev(
    const u16* __restrict__ A, int lda,
    const u16* __restrict__ B, int ldb,
    const float* __restrict__ bias,
    float* __restrict__ C, int ldc,
    u16* __restrict__ Cbf, int ldcb,
    float* __restrict__ aux,
    int M, int N, int KT, int bm, int bn, int ktb)
{
    constexpr int HALF = (BM + 128) * 128;
    constexpr int L    = (BM + 128) * 8 / 256;
    constexpr int MI   = BM / 32;

    __shared__ char lds[2 * HALF];

    const int tid = threadIdx.x, lane = tid & 63, wv = tid >> 6;
    const int wm = (wv >> 1) * (BM / 2), wn = (wv & 1) * 64;

    f32x4 acc[MI][4];
    #pragma unroll
    for (int i = 0; i < MI; ++i)
        #pragma unroll
        for (int j = 0; j < 4; ++j) acc[i][j] = (f32x4){0.f,0.f,0.f,0.f};

    auto stage = [&](int buf, int kt){
        const int kofs = kt * 64;
        #pragma unroll
        for (int i = 0; i < L; ++i) {
            int gb = i*256 + wv*64;
            int g  = gb + lane;
            const u16* src;
            if (i*256 < BM*8) {
                int row = g >> 3, slot = g & 7;
                src = A + (size_t)(bm + row)*lda + kofs + ((slot ^ (row & 7)) << 3);
            } else {
                int g2 = g - BM*8;
                int row = g2 >> 3, slot = g2 & 7;
                src = B + (size_t)(bn + row)*ldb + kofs + ((slot ^ (row & 7)) << 3);
            }
            gload16(src, lds + buf*HALF + gb*16);
        }
    };
    auto compute = [&](int buf){
        const char* Ab = lds + buf*HALF;
        const char* Bb = Ab + BM*128;
        #pragma unroll
        for (int kk = 0; kk < 2; ++kk) {
            int ks = kk*4 + (lane >> 4);
            bf16x8 af[MI], bfr[4];
            #pragma unroll
            for (int mi = 0; mi < MI; ++mi) {
                int row = wm + mi*16 + (lane & 15);
                af[mi] = *(const bf16x8*)(Ab + row*128 + ((ks ^ (row & 7)) << 4));
            }
            #pragma unroll
            for (int ni = 0; ni < 4; ++ni) {
                int n = wn + ni*16 + (lane & 15);
                bfr[ni] = *(const bf16x8*)(Bb + n*128 + ((ks ^ (n & 7)) << 4));
            }
            #pragma unroll
            for (int mi = 0; mi < MI; ++mi)
                #pragma unroll
                for (int ni = 0; ni < 4; ++ni)
                    acc[mi][ni] = __builtin_amdgcn_mfma_f32_16x16x32_bf16(
                        af[mi], bfr[ni], acc[mi][ni], 0, 0, 0);
        }
    };

    stage(0, ktb);
    int cur = 0;
    for (int t = 0; t < KT; ++t) {
        if (t + 1 < KT) {
            stage(cur ^ 1, ktb + t + 1);
            if constexpr (BM == 32) asm volatile("s_waitcnt vmcnt(5)" ::: "memory");
            else                    asm volatile("s_waitcnt vmcnt(6)" ::: "memory");
        } else {
            asm volatile("s_waitcnt vmcnt(0)" ::: "memory");
        }
        __builtin_amdgcn_sched_barrier(0);
        __builtin_amdgcn_s_barrier();
        __builtin_amdgcn_sched_barrier(0);
        compute(cur);
        __builtin_amdgcn_sched_barrier(0);
        __builtin_amdgcn_s_barrier();
        __builtin_amdgcn_sched_barrier(0);
        cur ^= 1;
    }

    const int rb = (lane >> 4) * 4, cb = lane & 15;
    #pragma unroll
    for (int mi = 0; mi < MI; ++mi) {
        #pragma unroll
        for (int r = 0; r < 4; ++r) {
            int row = bm + wm + mi*16 + rb + r;
            #pragma unroll
            for (int ni = 0; ni < 4; ++ni) {
                int col = bn + wn + ni*16 + cb;
                if (col >= N) continue;
                float v = acc[mi][ni][r];
                if (bias) v += bias[col];
                if (ACT == ACT_SILU)     v = siluf(v);
                if (ACT == ACT_GELU)     v = geluf(v);
                if (ACT == ACT_SOFTPLUS) v = softplusf(v);
                size_t idx = (size_t)row*ldc + col;
                if (MODE == 1)      C[idx] += v;
                else if (MODE == 2) { float t2 = v; if (aux) t2 += aux[idx]; atomicAdd(&C[idx], t2); }
                else if (MODE == 5) C[idx] = C[idx] + v + aux[idx];
                else if (MODE == 6) { float t2 = C[idx] + v; C[idx] = t2; aux[idx] = t2; }
                else {
                    if (MODE != 4) C[idx] = v;
                    if (MODE >= 3) Cbf[(size_t)row*ldcb + col] = bfbits(v);
                }
            }
        }
    }
    (void)M;
}

template<int BM, int ACT, int MODE>
__global__ __launch_bounds__(256) void gemm_g_bk(
    const u16* __restrict__ A, int lda, const u16* __restrict__ B, int ldb,
    const float* __restrict__ bias, float* __restrict__ C, int ldc,
    u16* __restrict__ Cbf, int ldcb, float* __restrict__ aux,
    int M, int N, int KT)
{
    if ((int)blockIdx.x * 128 >= N) return;   // XCD-pad idle tile
    const float* bias_eff = (blockIdx.z == 0) ? bias : nullptr;
    float*       aux_eff  = (blockIdx.z == 0) ? aux  : nullptr;
    gemm_dev<BM,ACT,MODE>(A,lda,B,ldb,bias_eff,C,ldc,Cbf,ldcb,aux_eff,M,N,KT,
                          blockIdx.y*BM, blockIdx.x*128, blockIdx.z*KT);
}

__global__ __launch_bounds__(256) void gemm_qkv_bk(
    const u16* __restrict__ A, const u16* __restrict__ Wqkv,
    const float* __restrict__ bq, const float* __restrict__ bk2, const float* __restrict__ bv,
    float* __restrict__ oq, float* __restrict__ ok2, float* __restrict__ ov)
{
    if ((int)blockIdx.x * 128 >= DTR_) return;   // XCD-pad idle tile (gx=16)
    int z = blockIdx.z;
    const float* bb = (z == 0) ? bq : (z == 1) ? bk2 : bv;
    float*       cc = (z == 0) ? oq : (z == 1) ? ok2 : ov;
    gemm_dev<64,ACT_NONE,0>(A, DTR_, Wqkv + (size_t)z*DTR_*DTR_, DTR_, bb,
                            cc, DTR_, nullptr, 0, nullptr, NB*NT, DTR_, 30,
                            blockIdx.y*64, blockIdx.x*128, 0);
}

__global__ __launch_bounds__(256) void gemm_memb_bk(
    const u16* __restrict__ A, const u16* __restrict__ W,
    const float* __restrict__ bias, float* __restrict__ Cc)
{
    int z = blockIdx.z;
    gemm_dev<32,ACT_NONE,0>(A, TEMPD, W + (size_t)z*DM*TEMPD, TEMPD, bias + (size_t)z*DM,
                            Cc + (size_t)z*NB*DM, DM, nullptr, 0, nullptr, NB, DM, 8,
                            blockIdx.y*32, blockIdx.x*128, 0);
}

__global__ __launch_bounds__(256) void gemm_ssb_bk(
    const u16* __restrict__ A, const u16* __restrict__ W,
    const float* __restrict__ b1, const float* __restrict__ b2, float* __restrict__ Cc)
{
    int z = blockIdx.z;
    const float* bb = (z < 4) ? b1 + (size_t)z*2*DTR_ : b2 + (size_t)(z-4)*2*DTR_;
    gemm_dev<32,ACT_NONE,0>(A, TEMPD, W + (size_t)z*2*DTR_*TEMPD, TEMPD, bb,
                            Cc + (size_t)z*NB*2*DTR_, 2*DTR_, nullptr, 0, nullptr, NB, 2*DTR_, 8,
                            blockIdx.y*32, blockIdx.x*128, 0);
}

// ---------------- weight convert (R7 version, proven): fp32[K,N] -> bf16[Np,Kp] plain transpose ----
struct ConvEnt { const float* src; u16* dst; int K, N, Kp, Np, tile0; };
struct ConvTab { ConvEnt e[64]; int n; };

__global__ __launch_bounds__(256) void wconv_k(ConvTab tab){
    int t = blockIdx.x;
    int i = 0;
    while (i + 1 < tab.n && tab.e[i+1].tile0 <= t) ++i;
    const float* src = tab.e[i].src;
    u16* dst = tab.e[i].dst;
    const int K = tab.e[i].K, N = tab.e[i].N, Kp = tab.e[i].Kp, Np = tab.e[i].Np;
    int lt = t - tab.e[i].tile0;
    int nx = Np >> 6;
    int n0 = (lt % nx) << 6, k0 = (lt / nx) << 6;

    __shared__ u16 tile[64][72];
    const int tid = threadIdx.x;
    {
        int r = tid >> 2, cs = (tid & 3) << 4;
        int gk = k0 + r;
        #pragma unroll
        for (int j = 0; j < 16; j += 4) {
            int gn = n0 + cs + j;
            float4 v = make_float4(0.f,0.f,0.f,0.f);
            if (gk < K) {
                if (gn + 3 < N) v = *(const float4*)(src + (size_t)gk*N + gn);
                else {
                    float tmp[4] = {0.f,0.f,0.f,0.f};
                    for (int e2 = 0; e2 < 4; ++e2) if (gn + e2 < N) tmp[e2] = src[(size_t)gk*N + gn + e2];
                    v = make_float4(tmp[0],tmp[1],tmp[2],tmp[3]);
                }
            }
            tile[r][cs+j+0] = bfbits(v.x);
            tile[r][cs+j+1] = bfbits(v.y);
            tile[r][cs+j+2] = bfbits(v.z);
            tile[r][cs+j+3] = bfbits(v.w);
        }
    }
    __syncthreads();
    {
        int n = tid >> 2, ks = (tid & 3) << 4;
        u16 outv[16];
        #pragma unroll
        for (int j = 0; j < 16; ++j) outv[j] = tile[ks + j][n];
        u16* dp = dst + (size_t)(n0 + n)*Kp + k0 + ks;
        *(uint4*)dp       = *(uint4*)&outv[0];
        *(uint4*)(dp + 8) = *(uint4*)&outv[8];
    }
}

// ---------------- small kernels ----------------

__global__ void tsemb_k(const int* __restrict__ t, u16* __restrict__ o){
    int b = blockIdx.x, j = threadIdx.x;   // 640
    float f = expf(-9.210340371976184f * (float)j / 640.f);
    float a = (float)t[b] * f;
    o[b*DM + j]       = bfbits(cosf(a));
    o[b*DM + 640 + j] = bfbits(sinf(a));
}

__global__ void silu_bf_v(const float* __restrict__ a, u16* __restrict__ o, int n){
    int i = blockIdx.x*256 + threadIdx.x; if (i < n) o[i] = bfbits(siluf(a[i]));
}
__global__ void zero_k(float* __restrict__ p, int n){
    int i = blockIdx.x*256 + threadIdx.x; if (i < n) p[i] = 0.f;
}

__global__ void embed_k(const float* __restrict__ x, const float* __restrict__ seq_emb,
                        const float* __restrict__ eW, const float* __restrict__ eb,
                        float* __restrict__ h, float* __restrict__ pre0){
    int i = blockIdx.x;            // b*600 + t*30 + vo
    int c = threadIdx.x;           // 64
    int vo = i % 30; int bt = i / 30; int t = bt % 20; int b = bt / 20;
    int v = d_VORDER[vo];
    const float* xp = x + (size_t)(b*20 + t)*48 + v*3;
    float val = eb[c] + seq_emb[(size_t)(t*16 + v)*64 + c]
              + xp[0]*eW[c] + xp[1]*eW[64 + c] + xp[2]*eW[128 + c];
    h[(size_t)i*64 + c] = val;
    pre0[(size_t)i*64 + c] = val;
}

__global__ void rms_t_k(const float* __restrict__ h, const float* __restrict__ w,
                        const float* __restrict__ memb,
                        float* __restrict__ hm, u16* __restrict__ hn_bf){
    int row = blockIdx.x;          // b*30+v
    int b = row / 30, v = row % 30;
    float ss = 0.f;
    for (int idx = threadIdx.x; idx < DM; idx += 256) {
        int t = idx >> 6, c = idx & 63;
        float val = h[((size_t)(b*20 + t)*30 + v)*64 + c];
        hm[(size_t)row*DM + idx] = val;
        ss += val*val;
    }
    ss = blockReduceSum(ss);
    float rs = rsqrtf(ss/(float)DM + 1e-5f);
    const float* ap = memb + (size_t)b*DM;
    for (int idx = threadIdx.x; idx < DM; idx += 256) {
        float val = hm[(size_t)row*DM + idx];
        hn_bf[(size_t)row*DM + idx] = bfbits(val*rs*w[idx] + ap[idx]);
    }
}

__global__ void hm2ht_ln_k(const float* __restrict__ hm, const float* __restrict__ w,
                           const float* __restrict__ bias,
                           float* __restrict__ h, u16* __restrict__ xn_bf){
    int row = blockIdx.x;          // b*20+t
    int b = row / 20, t = row % 20;
    float s1 = 0.f, s2 = 0.f;
    for (int idx = threadIdx.x; idx < DTR_; idx += 256) {
        int v = idx >> 6, c = idx & 63;
        float val = hm[((size_t)(b*30 + v))*DM + t*64 + c];
        h[(size_t)row*DTR_ + idx] = val;
        s1 += val; s2 += val*val;
    }
    s1 = blockReduceSum(s1);
    s2 = blockReduceSum(s2);
    float m = s1/(float)DTR_, var = s2/(float)DTR_ - m*m, rs = rsqrtf(var + 1e-5f);
    for (int idx = threadIdx.x; idx < DTR_; idx += 256) {
        float val = h[(size_t)row*DTR_ + idx];
        xn_bf[(size_t)row*DTR_ + idx] = bfbits((val - m)*rs*w[idx] + bias[idx]);
    }
}

__global__ void ln_bf_k(const float* __restrict__ x, const float* __restrict__ w,
                        const float* __restrict__ b, u16* __restrict__ obf, int D){
    int row = blockIdx.x;
    const float* xr = x + (size_t)row*D;
    float s1 = 0.f, s2 = 0.f;
    for (int i = threadIdx.x; i < D; i += 256){ float v = xr[i]; s1 += v; s2 += v*v; }
    s1 = blockReduceSum(s1);
    s2 = blockReduceSum(s2);
    float m = s1/(float)D, var = s2/(float)D - m*m, rs = rsqrtf(var + 1e-5f);
    for (int i = threadIdx.x; i < D; i += 256)
        obf[(size_t)row*D + i] = bfbits((xr[i] - m)*rs*w[i] + b[i]);
}

__global__ void convsilu_k(const float* __restrict__ xz, const float* __restrict__ cw,
                           const float* __restrict__ cb,
                           float* __restrict__ xc, u16* __restrict__ xcbf){
    int idx = blockIdx.x*256 + threadIdx.x;
    if (idx >= NB*NV*DI) return;
    int d = idx % DI; int bl = idx / DI; int l = bl % NV; int b = bl / NV;
    float acc = cb[d];
    #pragma unroll
    for (int k = 0; k < 4; ++k) {
        int ls = l - 3 + k;
        if (ls >= 0) acc += xz[((size_t)(b*NV + ls))*(2*DI) + d] * cw[d*4 + k];
    }
    float v = siluf(acc);
    xc[idx] = v;
    xcbf[idx] = bfbits(v);
}

__global__ void dbcconv_k(const float* __restrict__ dbc, u16* __restrict__ dbf){
    int i = blockIdx.x*256 + threadIdx.x;
    if (i >= NB*NV*128) return;
    int r = i >> 7, c = i & 127;
    dbf[i] = bfbits(c < 112 ? dbc[(size_t)r*112 + c] : 0.f);
}

__global__ __launch_bounds__(256) void scan_k(
    const float* __restrict__ delta, const float* __restrict__ dbc,
    const float* __restrict__ xc, const float* __restrict__ xz,
    const float* __restrict__ A_log, const float* __restrict__ Dp,
    u16* __restrict__ y2bf)
{
    __shared__ float sBC[30][32];
    int b = blockIdx.x / 10;
    int dblk = blockIdx.x % 10;
    int tid = threadIdx.x;
    for (int i = tid; i < 30*32; i += 256) {
        int l = i >> 5, j = i & 31;
        sBC[l][j] = dbc[((size_t)(b*NV + l))*112 + 80 + j];
    }
    __syncthreads();
    int d = dblk*256 + tid;
    float aA[16], s[16];
    #pragma unroll
    for (int n = 0; n < 16; ++n){ aA[n] = -expf(A_log[(size_t)d*16 + n]); s[n] = 0.f; }
    float dpv = Dp[d];
    for (int l = 0; l < NV; ++l) {
        size_t base = (size_t)(b*NV + l);
        float dv   = delta[base*DI + d];
        float xcv  = xc[base*DI + d];
        float resv = xz[base*(2*DI) + DI + d];
        float y = 0.f;
        #pragma unroll
        for (int n = 0; n < 16; ++n) {
            float dA = expf(dv*aA[n]);
            s[n] = dA*s[n] + dv*sBC[l][n]*xcv;
            y = fmaf(s[n], sBC[l][16 + n], y);
        }
        y2bf[base*DI + d] = bfbits((y + xcv*dpv) * siluf(resv));
    }
}

__global__ __launch_bounds__(64) void attn_k(const float* __restrict__ q,
                                             const float* __restrict__ k,
                                             const float* __restrict__ v,
                                             float* __restrict__ o){
    int idx = blockIdx.x;          // b*160 + t*8 + h
    int h = idx % 8; int bt = idx / 8; int t = bt % 20; int b = bt / 20;
    int lane = threadIdx.x;
    const float* qp = q + ((size_t)(b*20 + t))*DTR_ + h*DH;
    float qr[4];
    #pragma unroll
    for (int i = 0; i < 4; ++i){ int j = lane + i*64; qr[i] = (j < DH) ? qp[j] : 0.f; }
    __shared__ float sc[20];
    const float scale = 0.06454972243679028f;
    for (int s2 = 0; s2 < 20; ++s2) {
        const float* kp = k + ((size_t)(b*20 + s2))*DTR_ + h*DH;
        float p = 0.f;
        #pragma unroll
        for (int i = 0; i < 4; ++i){ int j = lane + i*64; if (j < DH) p = fmaf(qr[i], kp[j], p); }
        #pragma unroll
        for (int off = 32; off > 0; off >>= 1) p += __shfl_down(p, off, 64);
        if (lane == 0) sc[s2] = p*scale;
    }
    __syncthreads();
    float m = -1e30f;
    #pragma unroll
    for (int s2 = 0; s2 < 20; ++s2) m = fmaxf(m, sc[s2]);
    float ps[20]; float sum = 0.f;
    #pragma unroll
    for (int s2 = 0; s2 < 20; ++s2){ ps[s2] = expf(sc[s2] - m); sum += ps[s2]; }
    float inv = 1.f/sum;
    float acc[4] = {0.f,0.f,0.f,0.f};
    for (int s2 = 0; s2 < 20; ++s2) {
        const float* vp = v + ((size_t)(b*20 + s2))*DTR_ + h*DH;
        float w2 = ps[s2]*inv;
        #pragma unroll
        for (int i = 0; i < 4; ++i){ int j = lane + i*64; if (j < DH) acc[i] = fmaf(w2, vp[j], acc[i]); }
    }
    float* op = o + ((size_t)(b*20 + t))*DTR_ + h*DH;
    #pragma unroll
    for (int i = 0; i < 4; ++i){ int j = lane + i*64; if (j < DH) op[j] = acc[i]; }
}

__global__ void sty_ln_k(const float* __restrict__ x, const float* __restrict__ lw,
                         const float* __restrict__ lb, const float* __restrict__ ss,
                         u16* __restrict__ obf){
    int row = blockIdx.x;          // b*20+t
    int b = row / 20;
    const float* xr = x + (size_t)row*DTR_;
    float s1 = 0.f, s2 = 0.f;
    for (int i = threadIdx.x; i < DTR_; i += 256){ float v = xr[i]; s1 += v; s2 += v*v; }
    s1 = blockReduceSum(s1);
    s2 = blockReduceSum(s2);
    float m = s1/(float)DTR_, var = s2/(float)DTR_ - m*m, rs = rsqrtf(var + 1e-5f);
    const float* sb = ss + (size_t)b*(2*DTR_);
    for (int i = threadIdx.x; i < DTR_; i += 256) {
        float v = (xr[i] - m)*rs*lw[i] + lb[i];
        v = v*(1.f + sb[i]) + sb[DTR_ + i];
        obf[(size_t)row*DTR_ + i] = bfbits(siluf(v));
    }
}

__global__ void rms_f_k(const float* __restrict__ x, const float* __restrict__ w,
                        float* __restrict__ o, int D){
    int row = blockIdx.x;
    const float* xr = x + (size_t)row*D;
    float ss = 0.f;
    for (int i = threadIdx.x; i < D; i += 256){ float v = xr[i]; ss += v*v; }
    ss = blockReduceSum(ss);
    float rs = rsqrtf(ss/(float)D + 1e-5f);
    for (int i = threadIdx.x; i < D; i += 256)
        o[(size_t)row*D + i] = xr[i]*rs*w[i];
}

__global__ void head_k(const float* __restrict__ fr, const float* __restrict__ W,
                       const float* __restrict__ bias, float* __restrict__ out){
    int row = blockIdx.x;          // b*20+t
    int tid = threadIdx.x;         // 48
    int v = tid/3, j = tid%3;
    const float* g = fr + (size_t)row*DTR_ + d_REV[v]*64;
    float acc = bias[j];
    #pragma unroll
    for (int c = 0; c < 64; ++c) acc = fmaf(g[c], W[c*3 + j], acc);
    out[(size_t)row*48 + tid] = acc;
}

// ---------------- host-side GEMM launcher ----------------
template<int BM, int ACT, int MODE>
static void G(hipStream_t st, const u16* A, int lda, const u16* B, int ldb,
              const float* bias, float* C, int ldc, u16* Cbf, int ldcb,
              int M, int N, int KT, int splitZ = 1, float* aux = nullptr)
{
    int gx = (N + 127)/128;
    if (gx > 8) gx = (gx + 7) & ~7;   // XCD-concentrate B panels (stride % 8 == 0)
    dim3 g(gx, M/BM, splitZ), b(256);
    gemm_g_bk<BM,ACT,MODE><<<g, b, 0, st>>>(A,lda,B,ldb,bias,C,ldc,Cbf,ldcb,aux,M,N,KT);
}

// ---------------- orchestration ----------------
extern "C" void kernel_launch(void* const* d_in, const int* in_sizes, int n_in,
                              void* d_out, int out_size, void* d_ws, size_t ws_size,
                              hipStream_t stream)
{
    const float* x        = (const float*)d_in[0];
    const int*   tst      = (const int*)  d_in[1];
    const float* seq_emb  = (const float*)d_in[2];
    const float* emb_W    = (const float*)d_in[3];
    const float* emb_b    = (const float*)d_in[4];
    const float* time_W1  = (const float*)d_in[5];
    const float* time_b1  = (const float*)d_in[6];
    const float* time_W2  = (const float*)d_in[7];
    const float* time_b2  = (const float*)d_in[8];
    const float* m_norm_w = (const float*)d_in[9];
    const float* m_emb_W  = (const float*)d_in[10];
    const float* m_emb_b  = (const float*)d_in[11];
    const float* m_in_W   = (const float*)d_in[12];
    const float* m_conv_w = (const float*)d_in[13];
    const float* m_conv_b = (const float*)d_in[14];
    const float* m_xproj_W= (const float*)d_in[15];
    const float* m_dt_W   = (const float*)d_in[16];
    const float* m_dt_b   = (const float*)d_in[17];
    const float* m_A_log  = (const float*)d_in[18];
    const float* m_D      = (const float*)d_in[19];
    const float* m_out_W  = (const float*)d_in[20];
    const float* t_ln1_w  = (const float*)d_in[21];
    const float* t_ln1_b  = (const float*)d_in[22];
    const float* t_Wq     = (const float*)d_in[23];
    const float* t_bq     = (const float*)d_in[24];
    const float* t_Wk     = (const float*)d_in[25];
    const float* t_bk     = (const float*)d_in[26];
    const float* t_Wv     = (const float*)d_in[27];
    const float* t_bv     = (const float*)d_in[28];
    const float* t_s1_eW  = (const float*)d_in[29];
    const float* t_s1_eb  = (const float*)d_in[30];
    const float* t_s1_lw  = (const float*)d_in[31];
    const float* t_s1_lb  = (const float*)d_in[32];
    const float* t_s1_oW  = (const float*)d_in[33];
    const float* t_s1_ob  = (const float*)d_in[34];
    const float* t_ln2_w  = (const float*)d_in[35];
    const float* t_ln2_b  = (const float*)d_in[36];
    const float* t_fW1    = (const float*)d_in[37];
    const float* t_fb1    = (const float*)d_in[38];
    const float* t_fW2    = (const float*)d_in[39];
    const float* t_fb2    = (const float*)d_in[40];
    const float* t_s2_eW  = (const float*)d_in[41];
    const float* t_s2_eb  = (const float*)d_in[42];
    const float* t_s2_lw  = (const float*)d_in[43];
    const float* t_s2_lb  = (const float*)d_in[44];
    const float* t_s2_oW  = (const float*)d_in[45];
    const float* t_s2_ob  = (const float*)d_in[46];
    const float* normf_w  = (const float*)d_in[47];
    const float* head_W   = (const float*)d_in[48];
    const float* head_b   = (const float*)d_in[49];

    float* ws = (float*)d_ws;
    size_t off = 0;
    auto allocf = [&](size_t n){ float* p = ws + off; off += (n + 3) & ~(size_t)3; return p; };
    auto allocu = [&](size_t n){ return (u16*)allocf((n + 1) / 2); };

    const size_t HSZ = (size_t)NB*NT*NV*JLD;      // 1,228,800
    // fp32
    float* emb   = allocf((size_t)NB*TEMPD);
    float* memb4 = allocf((size_t)4*NB*DM);
    float* ssb8  = allocf((size_t)8*NB*2*DTR_);
    float* h     = allocf(HSZ);
    float* pre0  = allocf(HSZ);
    float* pre1  = allocf(HSZ);
    float* hm    = allocf(HSZ);
    float* qb    = allocf(HSZ);
    float* kb    = allocf(HSZ);
    float* vb    = allocf(HSZ);
    float* aty   = allocf(HSZ);
    float* fr    = allocf(HSZ);
    float* xz    = allocf((size_t)NB*NV*2*DI);
    float* xcb   = allocf((size_t)NB*NV*DI);
    float* dbc   = allocf((size_t)NB*NV*112);
    float* delta = allocf((size_t)NB*NV*DI);
    // bf16 activations
    u16* embt_bf = allocu((size_t)NB*DM);
    u16* emb1_bf = allocu((size_t)NB*TEMPD);
    u16* emb_bf  = allocu((size_t)NB*TEMPD);
    u16* semb_bf = allocu((size_t)NB*TEMPD);
    u16* hn_bf   = allocu((size_t)NB*NV*DM);
    u16* xcb_bf  = allocu((size_t)NB*NV*DI);
    u16* dbc_bf  = allocu((size_t)NB*NV*128);
    u16* y2_bf   = allocu((size_t)NB*NV*DI);
    u16* xn_bf   = allocu((size_t)NB*NT*DTR_);
    u16* sty_bf  = allocu((size_t)NB*NT*DTR_);
    u16* mid_bf  = allocu((size_t)NB*NT*DI);
    // bf16 weights (upfront, shared)
    u16* tw1   = allocu((size_t)TEMPD*DM);
    u16* tw2   = allocu((size_t)TEMPD*TEMPD);
    u16* membW = allocu((size_t)4*DM*TEMPD);
    u16* ssbW  = allocu((size_t)8*2*DTR_*TEMPD);
    // bf16 weight slabs, all 4 layers
    const size_t SLAB = (size_t)2*DI*DM + 128*DI + DI*128 + DM*DI
                      + (size_t)3*DTR_*DTR_ + 2*(size_t)DTR_*DTR_
                      + (size_t)DI*DTR_ + (size_t)DTR_*DI;
    u16* slab0 = allocu(SLAB*4);
    (void)ws_size; (void)in_sizes; (void)n_in; (void)out_size;

    // per-layer slab pointers
    u16 *s_in[4], *s_xp[4], *s_dt[4], *s_out[4], *s_qkv[4], *s_s1o[4], *s_s2o[4], *s_f1[4], *s_f2[4];
    for (int l = 0; l < 4; ++l) {
        u16* p = slab0 + SLAB*l;
        s_in[l]  = p; p += (size_t)2*DI*DM;
        s_xp[l]  = p; p += (size_t)128*DI;
        s_dt[l]  = p; p += (size_t)DI*128;
        s_out[l] = p; p += (size_t)DM*DI;
        s_qkv[l] = p; p += (size_t)3*DTR_*DTR_;
        s_s1o[l] = p; p += (size_t)DTR_*DTR_;
        s_s2o[l] = p; p += (size_t)DTR_*DTR_;
        s_f1[l]  = p; p += (size_t)DI*DTR_;
        s_f2[l]  = p;
    }

    auto tiles = [](int Kp, int Np){ return (Np/64)*(Kp/64); };

    // ---- ALL weight conversion in one launch (R7 wconv) ----
    {
        ConvTab tb; int n = 0, tot = 0;
        auto add = [&](const float* src, u16* dst, int K, int N){
            int Kp = (K + 63) & ~63;
            int Np = (N + 127) & ~127;
            tb.e[n] = {src, dst, K, N, Kp, Np, tot};
            tot += tiles(Kp, Np); ++n;
        };
        add(time_W1, tw1, DM, TEMPD);
        add(time_W2, tw2, TEMPD, TEMPD);
        for (int l = 0; l < 4; ++l)
            add(m_emb_W + (size_t)l*TEMPD*DM, membW + (size_t)l*DM*TEMPD, TEMPD, DM);
        for (int l = 0; l < 4; ++l)
            add(t_s1_eW + (size_t)l*TEMPD*2*DTR_, ssbW + (size_t)l*2*DTR_*TEMPD, TEMPD, 2*DTR_);
        for (int l = 0; l < 4; ++l)
            add(t_s2_eW + (size_t)l*TEMPD*2*DTR_, ssbW + (size_t)(4+l)*2*DTR_*TEMPD, TEMPD, 2*DTR_);
        for (int l = 0; l < 4; ++l) {
            add(m_in_W   + (size_t)l*DM*2*DI,     s_in[l],  DM, 2*DI);
            add(m_xproj_W+ (size_t)l*DI*112,      s_xp[l],  DI, 112);
            add(m_dt_W   + (size_t)l*DTRANK*DI,   s_dt[l],  DTRANK, DI);
            add(m_out_W  + (size_t)l*DI*DM,       s_out[l], DI, DM);
            add(t_Wq     + (size_t)l*DTR_*DTR_,   s_qkv[l],                       DTR_, DTR_);
            add(t_Wk     + (size_t)l*DTR_*DTR_,   s_qkv[l] + (size_t)DTR_*DTR_,   DTR_, DTR_);
            add(t_Wv     + (size_t)l*DTR_*DTR_,   s_qkv[l] + (size_t)2*DTR_*DTR_, DTR_, DTR_);
            add(t_s1_oW  + (size_t)l*DTR_*DTR_,   s_s1o[l], DTR_, DTR_);
            add(t_s2_oW  + (size_t)l*DTR_*DTR_,   s_s2o[l], DTR_, DTR_);
            add(t_fW1    + (size_t)l*DTR_*DI,     s_f1[l],  DTR_, DI);
            add(t_fW2    + (size_t)l*DI*DTR_,     s_f2[l],  DI, DTR_);
        }
        tb.n = n;
        wconv_k<<<tot, 256, 0, stream>>>(tb);
    }

    // ---- time embedding + MLP ----
    tsemb_k<<<NB, 640, 0, stream>>>(tst, embt_bf);
    G<32,ACT_SILU,4>(stream, embt_bf, DM, tw1, DM, time_b1, nullptr, 0, emb1_bf, TEMPD, NB, TEMPD, 20);
    G<32,ACT_NONE,3>(stream, emb1_bf, TEMPD, tw2, TEMPD, time_b2, emb, TEMPD, emb_bf, TEMPD, NB, TEMPD, 8);
    silu_bf_v<<<(NB*TEMPD + 255)/256, 256, 0, stream>>>(emb, semb_bf, NB*TEMPD);

    // ---- hoisted per-layer emb projections ----
    {
        dim3 g1(DM/128, 1, 4), b(256);
        gemm_memb_bk<<<g1, b, 0, stream>>>(emb_bf, membW, m_emb_b, memb4);
        dim3 g2((2*DTR_)/128, 1, 8);
        gemm_ssb_bk<<<g2, b, 0, stream>>>(semb_bf, ssbW, t_s1_eb, t_s2_eb, ssb8);
    }

    // ---- vertex embedding + VORDER gather (writes h and pre0) ----
    embed_k<<<NB*NT*NV, 64, 0, stream>>>(x, seq_emb, emb_W, emb_b, h, pre0);

    for (int i = 0; i < 4; ++i) {
        // ---- mamba half ----
        rms_t_k<<<NB*NV, 256, 0, stream>>>(h, m_norm_w + (size_t)i*DM,
                                           memb4 + (size_t)i*NB*DM, hm, hn_bf);
        // in_W: BM=64 (AI 43), 600 real blocks, nx=40
        G<64,ACT_NONE,0>(stream, hn_bf, DM, s_in[i], DM, nullptr, xz, 2*DI, nullptr, 0, NB*NV, 2*DI, 20);
        convsilu_k<<<(NB*NV*DI + 255)/256, 256, 0, stream>>>(
            xz, m_conv_w + (size_t)i*DI*4, m_conv_b + (size_t)i*DI, xcb, xcb_bf);
        zero_k<<<(NB*NV*112 + 255)/256, 256, 0, stream>>>(dbc, NB*NV*112);
        G<32,ACT_NONE,2>(stream, xcb_bf, DI, s_xp[i], DI, nullptr, dbc, 112, nullptr, 0, NB*NV, 112, 5, 8);
        dbcconv_k<<<(NB*NV*128 + 255)/256, 256, 0, stream>>>(dbc, dbc_bf);
        // dt: BM=32, nx padded 20->24
        G<32,ACT_SOFTPLUS,0>(stream, dbc_bf, 128, s_dt[i], 128, m_dt_b + (size_t)i*DI,
                             delta, DI, nullptr, 0, NB*NV, DI, 2);
        scan_k<<<NB*10, 256, 0, stream>>>(delta, dbc, xcb, xz,
             m_A_log + (size_t)i*DI*DSTATE, m_D + (size_t)i*DI, y2_bf);
        // out: split-K x2, atomic += into hm; nx padded 10->16
        G<32,ACT_NONE,2>(stream, y2_bf, DI, s_out[i], DI, nullptr, hm, DM, nullptr, 0, NB*NV, DM, 20, 2);
        hm2ht_ln_k<<<NB*NT, 256, 0, stream>>>(hm, t_ln1_w + (size_t)i*DTR_, t_ln1_b + (size_t)i*DTR_,
                                              h, xn_bf);

        // ---- transformer half ----
        {
            dim3 g(16, (NB*NT)/64, 3), b(256);   // BM=64: 16x10x3, gx padded 15->16
            gemm_qkv_bk<<<g, b, 0, stream>>>(xn_bf, s_qkv[i],
                t_bq + (size_t)i*DTR_, t_bk + (size_t)i*DTR_, t_bv + (size_t)i*DTR_,
                qb, kb, vb);
        }
        attn_k<<<NB*NT*NHEAD_, 64, 0, stream>>>(qb, kb, vb, aty);

        sty_ln_k<<<NB*NT, 256, 0, stream>>>(aty, t_s1_lw + (size_t)i*DTR_, t_s1_lb + (size_t)i*DTR_,
                                            ssb8 + (size_t)i*NB*2*DTR_, sty_bf);
        // s1o: split-K x2, atomic += into h, bias once; nx padded 15->16
        G<32,ACT_NONE,2>(stream, sty_bf, DTR_, s_s1o[i], DTR_, t_s1_ob + (size_t)i*DTR_,
                         h, DTR_, nullptr, 0, NB*NT, DTR_, 15, 2);

        ln_bf_k<<<NB*NT, 256, 0, stream>>>(h, t_ln2_w + (size_t)i*DTR_, t_ln2_b + (size_t)i*DTR_, xn_bf, DTR_);
        G<32,ACT_GELU,4>(stream, xn_bf, DTR_, s_f1[i], DTR_, t_fb1 + (size_t)i*DI,
                         nullptr, 0, mid_bf, DI, NB*NT, DI, 30);
        // f2: zero aty, then split-K x2 atomic store; nx padded 15->16
        zero_k<<<(int)((HSZ + 255)/256), 256, 0, stream>>>(aty, (int)HSZ);
        G<32,ACT_NONE,2>(stream, mid_bf, DI, s_f2[i], DI, t_fb2 + (size_t)i*DTR_,
                         aty, DTR_, nullptr, 0, NB*NT, DTR_, 20, 2);

        sty_ln_k<<<NB*NT, 256, 0, stream>>>(aty, t_s2_lw + (size_t)i*DTR_, t_s2_lb + (size_t)i*DTR_,
                                            ssb8 + (size_t)(4 + i)*NB*2*DTR_, sty_bf);
        if (i == 0)      // needs the completed sum copied to pre1 -> keep unsplit
            G<32,ACT_NONE,6>(stream, sty_bf, DTR_, s_s2o[i], DTR_, t_s2_ob + (size_t)i*DTR_,
                             h, DTR_, nullptr, 0, NB*NT, DTR_, 30, 1, pre1);
        else if (i == 2) // h += v + pre1 : split-K x2, aux added once by z==0
            G<32,ACT_NONE,2>(stream, sty_bf, DTR_, s_s2o[i], DTR_, t_s2_ob + (size_t)i*DTR_,
                             h, DTR_, nullptr, 0, NB*NT, DTR_, 15, 2, pre1);
        else if (i == 3)
            G<32,ACT_NONE,2>(stream, sty_bf, DTR_, s_s2o[i], DTR_, t_s2_ob + (size_t)i*DTR_,
                             h, DTR_, nullptr, 0, NB*NT, DTR_, 15, 2, pre0);
        else
            G<32,ACT_NONE,2>(stream, sty_bf, DTR_, s_s2o[i], DTR_, t_s2_ob + (size_t)i*DTR_,
                             h, DTR_, nullptr, 0, NB*NT, DTR_, 15, 2);
    }

    // final rmsnorm + REV gather + head
    rms_f_k<<<NB*NT, 256, 0, stream>>>(h, normf_w, fr, DTR_);
    head_k<<<NB*NT, 48, 0, stream>>>(fr, head_W, head_b, (float*)d_out);
}

// Round 16
// 1736.664 us; speedup vs baseline: 1.2074x; 1.0101x over previous
//
#include <hip/hip_runtime.h>
#include <hip/hip_bf16.h>
#include <math.h>

// ---------------- constants ----------------
#define NB 32
#define NT 20
#define NV 30
#define JLD 64
#define DM 1280
#define DTR_ 1920
#define DI 2560
#define DSTATE 16
#define DTRANK 80
#define TEMPD 512
#define NHEAD_ 8
#define DH 240

__constant__ int d_VORDER[30] = {9,8,7,10,11,12,11,10,7,13,14,15,14,13,7,6,0,1,2,1,0,6,3,4,5,4,3,6,7,8};
__constant__ int d_REV[16]    = {20,19,18,26,25,24,27,28,29,0,7,6,5,13,12,11};

typedef unsigned short u16;
typedef __bf16 bf16x8 __attribute__((ext_vector_type(8)));
typedef float f32x4  __attribute__((ext_vector_type(4)));

__device__ __forceinline__ float siluf(float x){ return x / (1.f + expf(-x)); }
__device__ __forceinline__ float geluf(float x){
    float x3 = x*x*x;
    return 0.5f*x*(1.f + tanhf(0.7978845608028654f*(x + 0.044715f*x3)));
}
__device__ __forceinline__ float softplusf(float x){
    return fmaxf(x, 0.f) + log1pf(expf(-fabsf(x)));
}
__device__ __forceinline__ u16 bfbits(float x){
    return __builtin_bit_cast(u16, (__bf16)x);
}

__device__ __forceinline__ void gload16(const void* g, void* l){
    __builtin_amdgcn_global_load_lds(
        (const __attribute__((address_space(1))) void*)g,
        (__attribute__((address_space(3))) void*)l, 16, 0, 0);
}

__device__ __forceinline__ float blockReduceSum(float v){
    #pragma unroll
    for (int off = 32; off > 0; off >>= 1) v += __shfl_down(v, off, 64);
    __shared__ float sred[4];
    __shared__ float stot;
    int w = threadIdx.x >> 6;
    if ((threadIdx.x & 63) == 0) sred[w] = v;
    __syncthreads();
    if (threadIdx.x == 0) stot = sred[0] + sred[1] + sred[2] + sred[3];
    __syncthreads();
    return stot;
}

enum { ACT_NONE=0, ACT_SILU=1, ACT_GELU=2, ACT_SOFTPLUS=3 };
// MODE: 0 store f32 | 1 += f32 | 2 atomicAdd f32 (+aux if non-null) | 3 store f32+bf16
//       4 store bf16 | 5 C += v + aux | 6 C += v, also write result to aux

// ---------------- bf16 MFMA GEMM, global_load_lds + counted vmcnt ----------------
template<int BM, int ACT, int MODE>
__device__ __forceinline__ void gemm_dev(
    const u16* __restrict__ A, int lda,
    const u16* __restrict__ B, int ldb,
    const float* __restrict__ bias,
    float* __restrict__ C, int ldc,
    u16* __restrict__ Cbf, int ldcb,
    float* __restrict__ aux,
    int M, int N, int KT, int bm, int bn, int ktb)
{
    constexpr int HALF = (BM + 128) * 128;
    constexpr int L    = (BM + 128) * 8 / 256;
    constexpr int MI   = BM / 32;

    __shared__ char lds[2 * HALF];

    const int tid = threadIdx.x, lane = tid & 63, wv = tid >> 6;
    const int wm = (wv >> 1) * (BM / 2), wn = (wv & 1) * 64;

    f32x4 acc[MI][4];
    #pragma unroll
    for (int i = 0; i < MI; ++i)
        #pragma unroll
        for (int j = 0; j < 4; ++j) acc[i][j] = (f32x4){0.f,0.f,0.f,0.f};

    auto stage = [&](int buf, int kt){
        const int kofs = kt * 64;
        #pragma unroll
        for (int i = 0; i < L; ++i) {
            int gb = i*256 + wv*64;
            int g  = gb + lane;
            const u16* src;
            if (i*256 < BM*8) {
                int row = g >> 3, slot = g & 7;
                src = A + (size_t)(bm + row)*lda + kofs + ((slot ^ (row & 7)) << 3);
            } else {
                int g2 = g - BM*8;
                int row = g2 >> 3, slot = g2 & 7;
                src = B + (size_t)(bn + row)*ldb + kofs + ((slot ^ (row & 7)) << 3);
            }
            gload16(src, lds + buf*HALF + gb*16);
        }
    };
    auto compute = [&](int buf){
        const char* Ab = lds + buf*HALF;
        const char* Bb = Ab + BM*128;
        #pragma unroll
        for (int kk = 0; kk < 2; ++kk) {
            int ks = kk*4 + (lane >> 4);
            bf16x8 af[MI], bfr[4];
            #pragma unroll
            for (int mi = 0; mi < MI; ++mi) {
                int row = wm + mi*16 + (lane & 15);
                af[mi] = *(const bf16x8*)(Ab + row*128 + ((ks ^ (row & 7)) << 4));
            }
            #pragma unroll
            for (int ni = 0; ni < 4; ++ni) {
                int n = wn + ni*16 + (lane & 15);
                bfr[ni] = *(const bf16x8*)(Bb + n*128 + ((ks ^ (n & 7)) << 4));
            }
            #pragma unroll
            for (int mi = 0; mi < MI; ++mi)
                #pragma unroll
                for (int ni = 0; ni < 4; ++ni)
                    acc[mi][ni] = __builtin_amdgcn_mfma_f32_16x16x32_bf16(
                        af[mi], bfr[ni], acc[mi][ni], 0, 0, 0);
        }
    };

    stage(0, ktb);
    int cur = 0;
    for (int t = 0; t < KT; ++t) {
        if (t + 1 < KT) {
            stage(cur ^ 1, ktb + t + 1);
            if constexpr (BM == 32) asm volatile("s_waitcnt vmcnt(5)" ::: "memory");
            else                    asm volatile("s_waitcnt vmcnt(6)" ::: "memory");
        } else {
            asm volatile("s_waitcnt vmcnt(0)" ::: "memory");
        }
        __builtin_amdgcn_sched_barrier(0);
        __builtin_amdgcn_s_barrier();
        __builtin_amdgcn_sched_barrier(0);
        compute(cur);
        __builtin_amdgcn_sched_barrier(0);
        __builtin_amdgcn_s_barrier();
        __builtin_amdgcn_sched_barrier(0);
        cur ^= 1;
    }

    const int rb = (lane >> 4) * 4, cb = lane & 15;
    #pragma unroll
    for (int mi = 0; mi < MI; ++mi) {
        #pragma unroll
        for (int r = 0; r < 4; ++r) {
            int row = bm + wm + mi*16 + rb + r;
            #pragma unroll
            for (int ni = 0; ni < 4; ++ni) {
                int col = bn + wn + ni*16 + cb;
                if (col >= N) continue;
                float v = acc[mi][ni][r];
                if (bias) v += bias[col];
                if (ACT == ACT_SILU)     v = siluf(v);
                if (ACT == ACT_GELU)     v = geluf(v);
                if (ACT == ACT_SOFTPLUS) v = softplusf(v);
                size_t idx = (size_t)row*ldc + col;
                if (MODE == 1)      C[idx] += v;
                else if (MODE == 2) { float t2 = v; if (aux) t2 += aux[idx]; atomicAdd(&C[idx], t2); }
                else if (MODE == 5) C[idx] = C[idx] + v + aux[idx];
                else if (MODE == 6) { float t2 = C[idx] + v; C[idx] = t2; aux[idx] = t2; }
                else {
                    if (MODE != 4) C[idx] = v;
                    if (MODE >= 3) Cbf[(size_t)row*ldcb + col] = bfbits(v);
                }
            }
        }
    }
    (void)M;
}

template<int BM, int ACT, int MODE>
__global__ __launch_bounds__(256) void gemm_g_bk(
    const u16* __restrict__ A, int lda, const u16* __restrict__ B, int ldb,
    const float* __restrict__ bias, float* __restrict__ C, int ldc,
    u16* __restrict__ Cbf, int ldcb, float* __restrict__ aux,
    int M, int N, int KT)
{
    if ((int)blockIdx.x * 128 >= N) return;   // XCD-pad idle tile
    const float* bias_eff = (blockIdx.z == 0) ? bias : nullptr;
    float*       aux_eff  = (blockIdx.z == 0) ? aux  : nullptr;
    gemm_dev<BM,ACT,MODE>(A,lda,B,ldb,bias_eff,C,ldc,Cbf,ldcb,aux_eff,M,N,KT,
                          blockIdx.y*BM, blockIdx.x*128, blockIdx.z*KT);
}

__global__ __launch_bounds__(256) void gemm_qkv_bk(
    const u16* __restrict__ A, const u16* __restrict__ Wqkv,
    const float* __restrict__ bq, const float* __restrict__ bk2, const float* __restrict__ bv,
    float* __restrict__ oq, float* __restrict__ ok2, float* __restrict__ ov)
{
    if ((int)blockIdx.x * 128 >= DTR_) return;   // XCD-pad idle tile (gx=16)
    int z = blockIdx.z;
    const float* bb = (z == 0) ? bq : (z == 1) ? bk2 : bv;
    float*       cc = (z == 0) ? oq : (z == 1) ? ok2 : ov;
    gemm_dev<64,ACT_NONE,0>(A, DTR_, Wqkv + (size_t)z*DTR_*DTR_, DTR_, bb,
                            cc, DTR_, nullptr, 0, nullptr, NB*NT, DTR_, 30,
                            blockIdx.y*64, blockIdx.x*128, 0);
}

__global__ __launch_bounds__(256) void gemm_memb_bk(
    const u16* __restrict__ A, const u16* __restrict__ W,
    const float* __restrict__ bias, float* __restrict__ Cc)
{
    int z = blockIdx.z;
    gemm_dev<32,ACT_NONE,0>(A, TEMPD, W + (size_t)z*DM*TEMPD, TEMPD, bias + (size_t)z*DM,
                            Cc + (size_t)z*NB*DM, DM, nullptr, 0, nullptr, NB, DM, 8,
                            blockIdx.y*32, blockIdx.x*128, 0);
}

__global__ __launch_bounds__(256) void gemm_ssb_bk(
    const u16* __restrict__ A, const u16* __restrict__ W,
    const float* __restrict__ b1, const float* __restrict__ b2, float* __restrict__ Cc)
{
    int z = blockIdx.z;
    const float* bb = (z < 4) ? b1 + (size_t)z*2*DTR_ : b2 + (size_t)(z-4)*2*DTR_;
    gemm_dev<32,ACT_NONE,0>(A, TEMPD, W + (size_t)z*2*DTR_*TEMPD, TEMPD, bb,
                            Cc + (size_t)z*NB*2*DTR_, 2*DTR_, nullptr, 0, nullptr, NB, 2*DTR_, 8,
                            blockIdx.y*32, blockIdx.x*128, 0);
}

// ---------------- weight convert (R7 version, proven): fp32[K,N] -> bf16[Np,Kp] plain transpose ----
struct ConvEnt { const float* src; u16* dst; int K, N, Kp, Np, tile0; };
struct ConvTab { ConvEnt e[64]; int n; };

__global__ __launch_bounds__(256) void wconv_k(ConvTab tab){
    int t = blockIdx.x;
    int i = 0;
    while (i + 1 < tab.n && tab.e[i+1].tile0 <= t) ++i;
    const float* src = tab.e[i].src;
    u16* dst = tab.e[i].dst;
    const int K = tab.e[i].K, N = tab.e[i].N, Kp = tab.e[i].Kp, Np = tab.e[i].Np;
    int lt = t - tab.e[i].tile0;
    int nx = Np >> 6;
    int n0 = (lt % nx) << 6, k0 = (lt / nx) << 6;

    __shared__ u16 tile[64][72];
    const int tid = threadIdx.x;
    {
        int r = tid >> 2, cs = (tid & 3) << 4;
        int gk = k0 + r;
        #pragma unroll
        for (int j = 0; j < 16; j += 4) {
            int gn = n0 + cs + j;
            float4 v = make_float4(0.f,0.f,0.f,0.f);
            if (gk < K) {
                if (gn + 3 < N) v = *(const float4*)(src + (size_t)gk*N + gn);
                else {
                    float tmp[4] = {0.f,0.f,0.f,0.f};
                    for (int e2 = 0; e2 < 4; ++e2) if (gn + e2 < N) tmp[e2] = src[(size_t)gk*N + gn + e2];
                    v = make_float4(tmp[0],tmp[1],tmp[2],tmp[3]);
                }
            }
            tile[r][cs+j+0] = bfbits(v.x);
            tile[r][cs+j+1] = bfbits(v.y);
            tile[r][cs+j+2] = bfbits(v.z);
            tile[r][cs+j+3] = bfbits(v.w);
        }
    }
    __syncthreads();
    {
        int n = tid >> 2, ks = (tid & 3) << 4;
        u16 outv[16];
        #pragma unroll
        for (int j = 0; j < 16; ++j) outv[j] = tile[ks + j][n];
        u16* dp = dst + (size_t)(n0 + n)*Kp + k0 + ks;
        *(uint4*)dp       = *(uint4*)&outv[0];
        *(uint4*)(dp + 8) = *(uint4*)&outv[8];
    }
}

// ---------------- small kernels ----------------

__global__ void tsemb_k(const int* __restrict__ t, u16* __restrict__ o){
    int b = blockIdx.x, j = threadIdx.x;   // 640
    float f = expf(-9.210340371976184f * (float)j / 640.f);
    float a = (float)t[b] * f;
    o[b*DM + j]       = bfbits(cosf(a));
    o[b*DM + 640 + j] = bfbits(sinf(a));
}

__global__ void silu_bf_v(const float* __restrict__ a, u16* __restrict__ o, int n){
    int i = blockIdx.x*256 + threadIdx.x; if (i < n) o[i] = bfbits(siluf(a[i]));
}

__global__ void embed_k(const float* __restrict__ x, const float* __restrict__ seq_emb,
                        const float* __restrict__ eW, const float* __restrict__ eb,
                        float* __restrict__ h, float* __restrict__ pre0){
    int i = blockIdx.x;            // b*600 + t*30 + vo
    int c = threadIdx.x;           // 64
    int vo = i % 30; int bt = i / 30; int t = bt % 20; int b = bt / 20;
    int v = d_VORDER[vo];
    const float* xp = x + (size_t)(b*20 + t)*48 + v*3;
    float val = eb[c] + seq_emb[(size_t)(t*16 + v)*64 + c]
              + xp[0]*eW[c] + xp[1]*eW[64 + c] + xp[2]*eW[128 + c];
    h[(size_t)i*64 + c] = val;
    pre0[(size_t)i*64 + c] = val;
}

__global__ void rms_t_k(const float* __restrict__ h, const float* __restrict__ w,
                        const float* __restrict__ memb,
                        float* __restrict__ hm, u16* __restrict__ hn_bf){
    int row = blockIdx.x;          // b*30+v
    int b = row / 30, v = row % 30;
    float ss = 0.f;
    for (int idx = threadIdx.x; idx < DM; idx += 256) {
        int t = idx >> 6, c = idx & 63;
        float val = h[((size_t)(b*20 + t)*30 + v)*64 + c];
        hm[(size_t)row*DM + idx] = val;
        ss += val*val;
    }
    ss = blockReduceSum(ss);
    float rs = rsqrtf(ss/(float)DM + 1e-5f);
    const float* ap = memb + (size_t)b*DM;
    for (int idx = threadIdx.x; idx < DM; idx += 256) {
        float val = hm[(size_t)row*DM + idx];
        hn_bf[(size_t)row*DM + idx] = bfbits(val*rs*w[idx] + ap[idx]);
    }
}

__global__ void hm2ht_ln_k(const float* __restrict__ hm, const float* __restrict__ w,
                           const float* __restrict__ bias,
                           float* __restrict__ h, u16* __restrict__ xn_bf){
    int row = blockIdx.x;          // b*20+t
    int b = row / 20, t = row % 20;
    float s1 = 0.f, s2 = 0.f;
    for (int idx = threadIdx.x; idx < DTR_; idx += 256) {
        int v = idx >> 6, c = idx & 63;
        float val = hm[((size_t)(b*30 + v))*DM + t*64 + c];
        h[(size_t)row*DTR_ + idx] = val;
        s1 += val; s2 += val*val;
    }
    s1 = blockReduceSum(s1);
    s2 = blockReduceSum(s2);
    float m = s1/(float)DTR_, var = s2/(float)DTR_ - m*m, rs = rsqrtf(var + 1e-5f);
    for (int idx = threadIdx.x; idx < DTR_; idx += 256) {
        float val = h[(size_t)row*DTR_ + idx];
        xn_bf[(size_t)row*DTR_ + idx] = bfbits((val - m)*rs*w[idx] + bias[idx]);
    }
}

// layernorm -> bf16; also zeroes zbuf row (fused aty-clear for the following split-K GEMM)
__global__ void ln_bf_k(const float* __restrict__ x, const float* __restrict__ w,
                        const float* __restrict__ b, u16* __restrict__ obf,
                        float* __restrict__ zbuf, int D){
    int row = blockIdx.x;
    const float* xr = x + (size_t)row*D;
    float s1 = 0.f, s2 = 0.f;
    for (int i = threadIdx.x; i < D; i += 256){ float v = xr[i]; s1 += v; s2 += v*v; }
    s1 = blockReduceSum(s1);
    s2 = blockReduceSum(s2);
    float m = s1/(float)D, var = s2/(float)D - m*m, rs = rsqrtf(var + 1e-5f);
    for (int i = threadIdx.x; i < D; i += 256) {
        obf[(size_t)row*D + i] = bfbits((xr[i] - m)*rs*w[i] + b[i]);
        if (zbuf) zbuf[(size_t)row*D + i] = 0.f;
    }
}

// conv+silu; also zeroes dbc (fused clear for the following xproj atomic GEMM)
__global__ void convsilu_k(const float* __restrict__ xz, const float* __restrict__ cw,
                           const float* __restrict__ cb,
                           float* __restrict__ xc, u16* __restrict__ xcbf,
                           float* __restrict__ dbc_z){
    int idx = blockIdx.x*256 + threadIdx.x;
    if (idx < NB*NV*112) dbc_z[idx] = 0.f;
    if (idx >= NB*NV*DI) return;
    int d = idx % DI; int bl = idx / DI; int l = bl % NV; int b = bl / NV;
    float acc = cb[d];
    #pragma unroll
    for (int k = 0; k < 4; ++k) {
        int ls = l - 3 + k;
        if (ls >= 0) acc += xz[((size_t)(b*NV + ls))*(2*DI) + d] * cw[d*4 + k];
    }
    float v = siluf(acc);
    xc[idx] = v;
    xcbf[idx] = bfbits(v);
}

__global__ void dbcconv_k(const float* __restrict__ dbc, u16* __restrict__ dbf){
    int i = blockIdx.x*256 + threadIdx.x;
    if (i >= NB*NV*128) return;
    int r = i >> 7, c = i & 127;
    dbf[i] = bfbits(c < 112 ? dbc[(size_t)r*112 + c] : 0.f);
}

__global__ __launch_bounds__(256) void scan_k(
    const float* __restrict__ delta, const float* __restrict__ dbc,
    const float* __restrict__ xc, const float* __restrict__ xz,
    const float* __restrict__ A_log, const float* __restrict__ Dp,
    u16* __restrict__ y2bf)
{
    __shared__ float sBC[30][32];
    int b = blockIdx.x / 10;
    int dblk = blockIdx.x % 10;
    int tid = threadIdx.x;
    for (int i = tid; i < 30*32; i += 256) {
        int l = i >> 5, j = i & 31;
        sBC[l][j] = dbc[((size_t)(b*NV + l))*112 + 80 + j];
    }
    __syncthreads();
    int d = dblk*256 + tid;
    float aA[16], s[16];
    #pragma unroll
    for (int n = 0; n < 16; ++n){ aA[n] = -expf(A_log[(size_t)d*16 + n]); s[n] = 0.f; }
    float dpv = Dp[d];
    for (int l = 0; l < NV; ++l) {
        size_t base = (size_t)(b*NV + l);
        float dv   = delta[base*DI + d];
        float xcv  = xc[base*DI + d];
        float resv = xz[base*(2*DI) + DI + d];
        float y = 0.f;
        #pragma unroll
        for (int n = 0; n < 16; ++n) {
            float dA = expf(dv*aA[n]);
            s[n] = dA*s[n] + dv*sBC[l][n]*xcv;
            y = fmaf(s[n], sBC[l][16 + n], y);
        }
        y2bf[base*DI + d] = bfbits((y + xcv*dpv) * siluf(resv));
    }
}

__global__ __launch_bounds__(64) void attn_k(const float* __restrict__ q,
                                             const float* __restrict__ k,
                                             const float* __restrict__ v,
                                             float* __restrict__ o){
    int idx = blockIdx.x;          // b*160 + t*8 + h
    int h = idx % 8; int bt = idx / 8; int t = bt % 20; int b = bt / 20;
    int lane = threadIdx.x;
    const float* qp = q + ((size_t)(b*20 + t))*DTR_ + h*DH;
    float qr[4];
    #pragma unroll
    for (int i = 0; i < 4; ++i){ int j = lane + i*64; qr[i] = (j < DH) ? qp[j] : 0.f; }
    __shared__ float sc[20];
    const float scale = 0.06454972243679028f;
    for (int s2 = 0; s2 < 20; ++s2) {
        const float* kp = k + ((size_t)(b*20 + s2))*DTR_ + h*DH;
        float p = 0.f;
        #pragma unroll
        for (int i = 0; i < 4; ++i){ int j = lane + i*64; if (j < DH) p = fmaf(qr[i], kp[j], p); }
        #pragma unroll
        for (int off = 32; off > 0; off >>= 1) p += __shfl_down(p, off, 64);
        if (lane == 0) sc[s2] = p*scale;
    }
    __syncthreads();
    float m = -1e30f;
    #pragma unroll
    for (int s2 = 0; s2 < 20; ++s2) m = fmaxf(m, sc[s2]);
    float ps[20]; float sum = 0.f;
    #pragma unroll
    for (int s2 = 0; s2 < 20; ++s2){ ps[s2] = expf(sc[s2] - m); sum += ps[s2]; }
    float inv = 1.f/sum;
    float acc[4] = {0.f,0.f,0.f,0.f};
    for (int s2 = 0; s2 < 20; ++s2) {
        const float* vp = v + ((size_t)(b*20 + s2))*DTR_ + h*DH;
        float w2 = ps[s2]*inv;
        #pragma unroll
        for (int i = 0; i < 4; ++i){ int j = lane + i*64; if (j < DH) acc[i] = fmaf(w2, vp[j], acc[i]); }
    }
    float* op = o + ((size_t)(b*20 + t))*DTR_ + h*DH;
    #pragma unroll
    for (int i = 0; i < 4; ++i){ int j = lane + i*64; if (j < DH) op[j] = acc[i]; }
}

__global__ void sty_ln_k(const float* __restrict__ x, const float* __restrict__ lw,
                         const float* __restrict__ lb, const float* __restrict__ ss,
                         u16* __restrict__ obf){
    int row = blockIdx.x;          // b*20+t
    int b = row / 20;
    const float* xr = x + (size_t)row*DTR_;
    float s1 = 0.f, s2 = 0.f;
    for (int i = threadIdx.x; i < DTR_; i += 256){ float v = xr[i]; s1 += v; s2 += v*v; }
    s1 = blockReduceSum(s1);
    s2 = blockReduceSum(s2);
    float m = s1/(float)DTR_, var = s2/(float)DTR_ - m*m, rs = rsqrtf(var + 1e-5f);
    const float* sb = ss + (size_t)b*(2*DTR_);
    for (int i = threadIdx.x; i < DTR_; i += 256) {
        float v = (xr[i] - m)*rs*lw[i] + lb[i];
        v = v*(1.f + sb[i]) + sb[DTR_ + i];
        obf[(size_t)row*DTR_ + i] = bfbits(siluf(v));
    }
}

__global__ void rms_f_k(const float* __restrict__ x, const float* __restrict__ w,
                        float* __restrict__ o, int D){
    int row = blockIdx.x;
    const float* xr = x + (size_t)row*D;
    float ss = 0.f;
    for (int i = threadIdx.x; i < D; i += 256){ float v = xr[i]; ss += v*v; }
    ss = blockReduceSum(ss);
    float rs = rsqrtf(ss/(float)D + 1e-5f);
    for (int i = threadIdx.x; i < D; i += 256)
        o[(size_t)row*D + i] = xr[i]*rs*w[i];
}

__global__ void head_k(const float* __restrict__ fr, const float* __restrict__ W,
                       const float* __restrict__ bias, float* __restrict__ out){
    int row = blockIdx.x;          // b*20+t
    int tid = threadIdx.x;         // 48
    int v = tid/3, j = tid%3;
    const float* g = fr + (size_t)row*DTR_ + d_REV[v]*64;
    float acc = bias[j];
    #pragma unroll
    for (int c = 0; c < 64; ++c) acc = fmaf(g[c], W[c*3 + j], acc);
    out[(size_t)row*48 + tid] = acc;
}

// ---------------- host-side GEMM launcher ----------------
template<int BM, int ACT, int MODE>
static void G(hipStream_t st, const u16* A, int lda, const u16* B, int ldb,
              const float* bias, float* C, int ldc, u16* Cbf, int ldcb,
              int M, int N, int KT, int splitZ = 1, float* aux = nullptr)
{
    int gx = (N + 127)/128;
    if (gx > 8) gx = (gx + 7) & ~7;   // XCD-concentrate B panels (stride % 8 == 0)
    dim3 g(gx, M/BM, splitZ), b(256);
    gemm_g_bk<BM,ACT,MODE><<<g, b, 0, st>>>(A,lda,B,ldb,bias,C,ldc,Cbf,ldcb,aux,M,N,KT);
}

// ---------------- orchestration ----------------
extern "C" void kernel_launch(void* const* d_in, const int* in_sizes, int n_in,
                              void* d_out, int out_size, void* d_ws, size_t ws_size,
                              hipStream_t stream)
{
    const float* x        = (const float*)d_in[0];
    const int*   tst      = (const int*)  d_in[1];
    const float* seq_emb  = (const float*)d_in[2];
    const float* emb_W    = (const float*)d_in[3];
    const float* emb_b    = (const float*)d_in[4];
    const float* time_W1  = (const float*)d_in[5];
    const float* time_b1  = (const float*)d_in[6];
    const float* time_W2  = (const float*)d_in[7];
    const float* time_b2  = (const float*)d_in[8];
    const float* m_norm_w = (const float*)d_in[9];
    const float* m_emb_W  = (const float*)d_in[10];
    const float* m_emb_b  = (const float*)d_in[11];
    const float* m_in_W   = (const float*)d_in[12];
    const float* m_conv_w = (const float*)d_in[13];
    const float* m_conv_b = (const float*)d_in[14];
    const float* m_xproj_W= (const float*)d_in[15];
    const float* m_dt_W   = (const float*)d_in[16];
    const float* m_dt_b   = (const float*)d_in[17];
    const float* m_A_log  = (const float*)d_in[18];
    const float* m_D      = (const float*)d_in[19];
    const float* m_out_W  = (const float*)d_in[20];
    const float* t_ln1_w  = (const float*)d_in[21];
    const float* t_ln1_b  = (const float*)d_in[22];
    const float* t_Wq     = (const float*)d_in[23];
    const float* t_bq     = (const float*)d_in[24];
    const float* t_Wk     = (const float*)d_in[25];
    const float* t_bk     = (const float*)d_in[26];
    const float* t_Wv     = (const float*)d_in[27];
    const float* t_bv     = (const float*)d_in[28];
    const float* t_s1_eW  = (const float*)d_in[29];
    const float* t_s1_eb  = (const float*)d_in[30];
    const float* t_s1_lw  = (const float*)d_in[31];
    const float* t_s1_lb  = (const float*)d_in[32];
    const float* t_s1_oW  = (const float*)d_in[33];
    const float* t_s1_ob  = (const float*)d_in[34];
    const float* t_ln2_w  = (const float*)d_in[35];
    const float* t_ln2_b  = (const float*)d_in[36];
    const float* t_fW1    = (const float*)d_in[37];
    const float* t_fb1    = (const float*)d_in[38];
    const float* t_fW2    = (const float*)d_in[39];
    const float* t_fb2    = (const float*)d_in[40];
    const float* t_s2_eW  = (const float*)d_in[41];
    const float* t_s2_eb  = (const float*)d_in[42];
    const float* t_s2_lw  = (const float*)d_in[43];
    const float* t_s2_lb  = (const float*)d_in[44];
    const float* t_s2_oW  = (const float*)d_in[45];
    const float* t_s2_ob  = (const float*)d_in[46];
    const float* normf_w  = (const float*)d_in[47];
    const float* head_W   = (const float*)d_in[48];
    const float* head_b   = (const float*)d_in[49];

    float* ws = (float*)d_ws;
    size_t off = 0;
    auto allocf = [&](size_t n){ float* p = ws + off; off += (n + 3) & ~(size_t)3; return p; };
    auto allocu = [&](size_t n){ return (u16*)allocf((n + 1) / 2); };

    const size_t HSZ = (size_t)NB*NT*NV*JLD;      // 1,228,800
    // fp32
    float* emb   = allocf((size_t)NB*TEMPD);
    float* memb4 = allocf((size_t)4*NB*DM);
    float* ssb8  = allocf((size_t)8*NB*2*DTR_);
    float* h     = allocf(HSZ);
    float* pre0  = allocf(HSZ);
    float* pre1  = allocf(HSZ);
    float* hm    = allocf(HSZ);
    float* qb    = allocf(HSZ);
    float* kb    = allocf(HSZ);
    float* vb    = allocf(HSZ);
    float* aty   = allocf(HSZ);
    float* fr    = allocf(HSZ);
    float* xz    = allocf((size_t)NB*NV*2*DI);
    float* xcb   = allocf((size_t)NB*NV*DI);
    float* dbc   = allocf((size_t)NB*NV*112);
    float* delta = allocf((size_t)NB*NV*DI);
    // bf16 activations
    u16* embt_bf = allocu((size_t)NB*DM);
    u16* emb1_bf = allocu((size_t)NB*TEMPD);
    u16* emb_bf  = allocu((size_t)NB*TEMPD);
    u16* semb_bf = allocu((size_t)NB*TEMPD);
    u16* hn_bf   = allocu((size_t)NB*NV*DM);
    u16* xcb_bf  = allocu((size_t)NB*NV*DI);
    u16* dbc_bf  = allocu((size_t)NB*NV*128);
    u16* y2_bf   = allocu((size_t)NB*NV*DI);
    u16* xn_bf   = allocu((size_t)NB*NT*DTR_);
    u16* sty_bf  = allocu((size_t)NB*NT*DTR_);
    u16* mid_bf  = allocu((size_t)NB*NT*DI);
    // bf16 weights (upfront, shared)
    u16* tw1   = allocu((size_t)TEMPD*DM);
    u16* tw2   = allocu((size_t)TEMPD*TEMPD);
    u16* membW = allocu((size_t)4*DM*TEMPD);
    u16* ssbW  = allocu((size_t)8*2*DTR_*TEMPD);
    // bf16 weight slabs, all 4 layers
    const size_t SLAB = (size_t)2*DI*DM + 128*DI + DI*128 + DM*DI
                      + (size_t)3*DTR_*DTR_ + 2*(size_t)DTR_*DTR_
                      + (size_t)DI*DTR_ + (size_t)DTR_*DI;
    u16* slab0 = allocu(SLAB*4);
    (void)ws_size; (void)in_sizes; (void)n_in; (void)out_size;

    // per-layer slab pointers
    u16 *s_in[4], *s_xp[4], *s_dt[4], *s_out[4], *s_qkv[4], *s_s1o[4], *s_s2o[4], *s_f1[4], *s_f2[4];
    for (int l = 0; l < 4; ++l) {
        u16* p = slab0 + SLAB*l;
        s_in[l]  = p; p += (size_t)2*DI*DM;
        s_xp[l]  = p; p += (size_t)128*DI;
        s_dt[l]  = p; p += (size_t)DI*128;
        s_out[l] = p; p += (size_t)DM*DI;
        s_qkv[l] = p; p += (size_t)3*DTR_*DTR_;
        s_s1o[l] = p; p += (size_t)DTR_*DTR_;
        s_s2o[l] = p; p += (size_t)DTR_*DTR_;
        s_f1[l]  = p; p += (size_t)DI*DTR_;
        s_f2[l]  = p;
    }

    auto tiles = [](int Kp, int Np){ return (Np/64)*(Kp/64); };

    // ---- ALL weight conversion in one launch (R7 wconv) ----
    {
        ConvTab tb; int n = 0, tot = 0;
        auto add = [&](const float* src, u16* dst, int K, int N){
            int Kp = (K + 63) & ~63;
            int Np = (N + 127) & ~127;
            tb.e[n] = {src, dst, K, N, Kp, Np, tot};
            tot += tiles(Kp, Np); ++n;
        };
        add(time_W1, tw1, DM, TEMPD);
        add(time_W2, tw2, TEMPD, TEMPD);
        for (int l = 0; l < 4; ++l)
            add(m_emb_W + (size_t)l*TEMPD*DM, membW + (size_t)l*DM*TEMPD, TEMPD, DM);
        for (int l = 0; l < 4; ++l)
            add(t_s1_eW + (size_t)l*TEMPD*2*DTR_, ssbW + (size_t)l*2*DTR_*TEMPD, TEMPD, 2*DTR_);
        for (int l = 0; l < 4; ++l)
            add(t_s2_eW + (size_t)l*TEMPD*2*DTR_, ssbW + (size_t)(4+l)*2*DTR_*TEMPD, TEMPD, 2*DTR_);
        for (int l = 0; l < 4; ++l) {
            add(m_in_W   + (size_t)l*DM*2*DI,     s_in[l],  DM, 2*DI);
            add(m_xproj_W+ (size_t)l*DI*112,      s_xp[l],  DI, 112);
            add(m_dt_W   + (size_t)l*DTRANK*DI,   s_dt[l],  DTRANK, DI);
            add(m_out_W  + (size_t)l*DI*DM,       s_out[l], DI, DM);
            add(t_Wq     + (size_t)l*DTR_*DTR_,   s_qkv[l],                       DTR_, DTR_);
            add(t_Wk     + (size_t)l*DTR_*DTR_,   s_qkv[l] + (size_t)DTR_*DTR_,   DTR_, DTR_);
            add(t_Wv     + (size_t)l*DTR_*DTR_,   s_qkv[l] + (size_t)2*DTR_*DTR_, DTR_, DTR_);
            add(t_s1_oW  + (size_t)l*DTR_*DTR_,   s_s1o[l], DTR_, DTR_);
            add(t_s2_oW  + (size_t)l*DTR_*DTR_,   s_s2o[l], DTR_, DTR_);
            add(t_fW1    + (size_t)l*DTR_*DI,     s_f1[l],  DTR_, DI);
            add(t_fW2    + (size_t)l*DI*DTR_,     s_f2[l],  DI, DTR_);
        }
        tb.n = n;
        wconv_k<<<tot, 256, 0, stream>>>(tb);
    }

    // ---- time embedding + MLP ----
    tsemb_k<<<NB, 640, 0, stream>>>(tst, embt_bf);
    G<32,ACT_SILU,4>(stream, embt_bf, DM, tw1, DM, time_b1, nullptr, 0, emb1_bf, TEMPD, NB, TEMPD, 20);
    G<32,ACT_NONE,3>(stream, emb1_bf, TEMPD, tw2, TEMPD, time_b2, emb, TEMPD, emb_bf, TEMPD, NB, TEMPD, 8);
    silu_bf_v<<<(NB*TEMPD + 255)/256, 256, 0, stream>>>(emb, semb_bf, NB*TEMPD);

    // ---- hoisted per-layer emb projections ----
    {
        dim3 g1(DM/128, 1, 4), b(256);
        gemm_memb_bk<<<g1, b, 0, stream>>>(emb_bf, membW, m_emb_b, memb4);
        dim3 g2((2*DTR_)/128, 1, 8);
        gemm_ssb_bk<<<g2, b, 0, stream>>>(semb_bf, ssbW, t_s1_eb, t_s2_eb, ssb8);
    }

    // ---- vertex embedding + VORDER gather (writes h and pre0) ----
    embed_k<<<NB*NT*NV, 64, 0, stream>>>(x, seq_emb, emb_W, emb_b, h, pre0);

    for (int i = 0; i < 4; ++i) {
        // ---- mamba half ----
        rms_t_k<<<NB*NV, 256, 0, stream>>>(h, m_norm_w + (size_t)i*DM,
                                           memb4 + (size_t)i*NB*DM, hm, hn_bf);
        // in_W: BM=64 (AI 43), 600 real blocks, nx=40
        G<64,ACT_NONE,0>(stream, hn_bf, DM, s_in[i], DM, nullptr, xz, 2*DI, nullptr, 0, NB*NV, 2*DI, 20);
        convsilu_k<<<(NB*NV*DI + 255)/256, 256, 0, stream>>>(
            xz, m_conv_w + (size_t)i*DI*4, m_conv_b + (size_t)i*DI, xcb, xcb_bf, dbc);
        G<32,ACT_NONE,2>(stream, xcb_bf, DI, s_xp[i], DI, nullptr, dbc, 112, nullptr, 0, NB*NV, 112, 5, 8);
        dbcconv_k<<<(NB*NV*128 + 255)/256, 256, 0, stream>>>(dbc, dbc_bf);
        // dt: BM=32, nx padded 20->24
        G<32,ACT_SOFTPLUS,0>(stream, dbc_bf, 128, s_dt[i], 128, m_dt_b + (size_t)i*DI,
                             delta, DI, nullptr, 0, NB*NV, DI, 2);
        scan_k<<<NB*10, 256, 0, stream>>>(delta, dbc, xcb, xz,
             m_A_log + (size_t)i*DI*DSTATE, m_D + (size_t)i*DI, y2_bf);
        // out: split-K x2, atomic += into hm; nx padded 10->16
        G<32,ACT_NONE,2>(stream, y2_bf, DI, s_out[i], DI, nullptr, hm, DM, nullptr, 0, NB*NV, DM, 20, 2);
        hm2ht_ln_k<<<NB*NT, 256, 0, stream>>>(hm, t_ln1_w + (size_t)i*DTR_, t_ln1_b + (size_t)i*DTR_,
                                              h, xn_bf);

        // ---- transformer half ----
        {
            dim3 g(16, (NB*NT)/64, 3), b(256);   // BM=64: 16x10x3, gx padded 15->16
            gemm_qkv_bk<<<g, b, 0, stream>>>(xn_bf, s_qkv[i],
                t_bq + (size_t)i*DTR_, t_bk + (size_t)i*DTR_, t_bv + (size_t)i*DTR_,
                qb, kb, vb);
        }
        attn_k<<<NB*NT*NHEAD_, 64, 0, stream>>>(qb, kb, vb, aty);

        sty_ln_k<<<NB*NT, 256, 0, stream>>>(aty, t_s1_lw + (size_t)i*DTR_, t_s1_lb + (size_t)i*DTR_,
                                            ssb8 + (size_t)i*NB*2*DTR_, sty_bf);
        // s1o: split-K x2, atomic += into h, bias once; nx padded 15->16
        G<32,ACT_NONE,2>(stream, sty_bf, DTR_, s_s1o[i], DTR_, t_s1_ob + (size_t)i*DTR_,
                         h, DTR_, nullptr, 0, NB*NT, DTR_, 15, 2);

        // ln2 also zeroes aty for the following split-K f2 accumulation
        ln_bf_k<<<NB*NT, 256, 0, stream>>>(h, t_ln2_w + (size_t)i*DTR_, t_ln2_b + (size_t)i*DTR_,
                                           xn_bf, aty, DTR_);
        G<32,ACT_GELU,4>(stream, xn_bf, DTR_, s_f1[i], DTR_, t_fb1 + (size_t)i*DI,
                         nullptr, 0, mid_bf, DI, NB*NT, DI, 30);
        G<32,ACT_NONE,2>(stream, mid_bf, DI, s_f2[i], DI, t_fb2 + (size_t)i*DTR_,
                         aty, DTR_, nullptr, 0, NB*NT, DTR_, 20, 2);

        sty_ln_k<<<NB*NT, 256, 0, stream>>>(aty, t_s2_lw + (size_t)i*DTR_, t_s2_lb + (size_t)i*DTR_,
                                            ssb8 + (size_t)(4 + i)*NB*2*DTR_, sty_bf);
        if (i == 0)      // needs the completed sum copied to pre1 -> keep unsplit
            G<32,ACT_NONE,6>(stream, sty_bf, DTR_, s_s2o[i], DTR_, t_s2_ob + (size_t)i*DTR_,
                             h, DTR_, nullptr, 0, NB*NT, DTR_, 30, 1, pre1);
        else if (i == 2) // h += v + pre1 : split-K x2, aux added once by z==0
            G<32,ACT_NONE,2>(stream, sty_bf, DTR_, s_s2o[i], DTR_, t_s2_ob + (size_t)i*DTR_,
                             h, DTR_, nullptr, 0, NB*NT, DTR_, 15, 2, pre1);
        else if (i == 3)
            G<32,ACT_NONE,2>(stream, sty_bf, DTR_, s_s2o[i], DTR_, t_s2_ob + (size_t)i*DTR_,
                             h, DTR_, nullptr, 0, NB*NT, DTR_, 15, 2, pre0);
        else
            G<32,ACT_NONE,2>(stream, sty_bf, DTR_, s_s2o[i], DTR_, t_s2_ob + (size_t)i*DTR_,
                             h, DTR_, nullptr, 0, NB*NT, DTR_, 15, 2);
    }

    // final rmsnorm + REV gather + head
    rms_f_k<<<NB*NT, 256, 0, stream>>>(h, normf_w, fr, DTR_);
    head_k<<<NB*NT, 48, 0, stream>>>(fr, head_W, head_b, (float*)d_out);
}